// Round 4
// baseline (474.704 us; speedup 1.0000x reference)
//
#include <hip/hip_runtime.h>
#include <hip/hip_bf16.h>
#include <math.h>

// Problem constants (from reference)
#define NN 100000      // nodes
#define NP 3           // metapaths
#define NE 800000      // edges per path
#define NH 4           // heads
#define ND 32          // dim per head
#define HD 128         // H*D
#define NHID 64        // semantic hidden

// fill/gather geometry
#define SLW 256        // nodes per bucket (pow2: sl = d>>8, dl = d&255)
#define SBK 512        // bucket slots (>= ceil(NN/SLW)=391; 391..511 stay empty)
#define GB 391         // used buckets = ceil(NN/SLW)
#define NBLK 196       // fillA blocks per path = ceil(NE/4096)
#define ECHUNK 4096    // edges per fillA block
#define EPT 16         // edges per thread in fillA (256 thr)
#define EMAX 2560      // per-bucket edge cap: mean 2048, sigma 45 -> +11 sigma

typedef __attribute__((ext_vector_type(8))) short short8;
typedef __attribute__((ext_vector_type(4))) float f32x4;

__device__ __forceinline__ unsigned short f2bf(float f) {
  union { float f; unsigned int u; } v; v.f = f;
  unsigned int r = v.u + 0x7FFFu + ((v.u >> 16) & 1u);   // round-to-nearest-even
  return (unsigned short)(r >> 16);
}
__device__ __forceinline__ float bf2f(unsigned short u) {
  return __uint_as_float(((unsigned int)u) << 16);
}
__device__ __forceinline__ float tanh_fast(float x) {
  return 1.f - 2.f / (1.f + __expf(2.f * x));   // saturates correctly
}

// ---------------- prep + fillA fused ----------------
// Blocks [0,12500): cast h->bf16, transpose/cast W,W1, zero s.
// Blocks [12500,12500+3*196): fillA — per-block-exclusive counting compaction:
//   each 4096-edge chunk LDS-histograms by bucket (d>>8), scans, writes edges densely
//   into its own pairs segment; per-(block,bucket) count+base to cntA/baseA.
//   No shared global counters -> no pre-zero dependency -> fused with prep for overlap.
//   Dense packed writes keep writeback == payload (R1 lesson: scattered 4B stores
//   caused 13x write amplification).
__global__ __launch_bounds__(256) void prep_fill_kernel(
    const float* __restrict__ h, const float* __restrict__ W, const float* __restrict__ W1,
    const int* __restrict__ src_all, const int* __restrict__ dst_all,
    unsigned short* __restrict__ hb, unsigned short* __restrict__ WT,
    unsigned short* __restrict__ W1T, float* __restrict__ s,
    int* __restrict__ cntA, int* __restrict__ baseA, int* __restrict__ pairs) {
  __shared__ int hist[SBK];
  __shared__ int scanb[SBK];
  const int tid = threadIdx.x;
  const int bx = blockIdx.x;
  if (bx < 12500) {
    int i = bx * 256 + tid;
    if (i < NN * 32) {                       // cast h, 4 elems per thread
      float4 v = ((const float4*)h)[i];
      ushort4 o;
      o.x = f2bf(v.x); o.y = f2bf(v.y); o.z = f2bf(v.z); o.w = f2bf(v.w);
      ((ushort4*)hb)[i] = o;
    }
    if (i < NP * 128 * 128) {                // WT[p][n][k] = W[p][k][n]
      int p = i >> 14, r = i & 16383, n = r >> 7, k = r & 127;
      WT[i] = f2bf(W[(size_t)p * 16384 + k * 128 + n]);
    }
    if (i < NHID * 128) {                    // W1T[n][k] = W1[k][n]
      int n = i >> 7, k = i & 127;
      W1T[i] = f2bf(W1[(size_t)k * NHID + n]);
    }
    if (i < 4) s[i] = 0.f;
    return;
  }
  // ---- fillA ----
  const int b2 = bx - 12500;
  const int p = b2 / NBLK, blk = b2 % NBLK;
  const int* dstp = dst_all + (size_t)p * NE;
  const int* srcp = src_all + (size_t)p * NE;
  hist[tid] = 0; hist[tid + 256] = 0;
  __syncthreads();
  int dv[EPT], sv[EPT];
#pragma unroll
  for (int k = 0; k < EPT; ++k) {
    int e = blk * ECHUNK + k * 256 + tid;
    dv[k] = -1; sv[k] = 0;
    if (e < NE) {
      dv[k] = __builtin_nontemporal_load(dstp + e);
      sv[k] = __builtin_nontemporal_load(srcp + e);
    }
    if (dv[k] >= 0) atomicAdd(&hist[(unsigned)dv[k] >> 8], 1);
  }
  __syncthreads();
  // inclusive scan of hist (512 entries, 2 per thread, Hillis-Steele)
  scanb[tid] = hist[tid]; scanb[tid + 256] = hist[tid + 256];
  __syncthreads();
  for (int off = 1; off < SBK; off <<= 1) {
    int a0 = (tid >= off) ? scanb[tid - off] : 0;
    int a1 = scanb[tid + 256 - off];          // tid+256 >= off always (off<=256)
    __syncthreads();
    scanb[tid] += a0; scanb[tid + 256] += a1;
    __syncthreads();
  }
  // exclusive base; record counts+bases; reset hist as scatter cursor
  int c0 = hist[tid], c1 = hist[tid + 256];
  int b0 = scanb[tid] - c0, b1 = scanb[tid + 256] - c1;
  int* cA = cntA + ((size_t)p * NBLK + blk) * SBK;
  int* bA = baseA + ((size_t)p * NBLK + blk) * SBK;
  cA[tid] = c0; cA[tid + 256] = c1;
  bA[tid] = b0; bA[tid + 256] = b1;
  __syncthreads();
  scanb[tid] = b0; scanb[tid + 256] = b1;
  hist[tid] = 0; hist[tid + 256] = 0;
  __syncthreads();
  int* prp = pairs + (size_t)p * NE + (size_t)blk * ECHUNK;
#pragma unroll
  for (int k = 0; k < EPT; ++k) {
    if (dv[k] >= 0) {
      int sl = (unsigned)dv[k] >> 8;
      int pos = scanb[sl] + atomicAdd(&hist[sl], 1);
      prp[pos] = ((dv[k] & 255) << 17) | sv[k];    // src < 2^17
    }
  }
}

// ---------------- MFMA feature GEMM (all paths) + fused el/er ----------------
// grid (NN/64, NP); block 256 = 4 waves; each wave one 16-row tile; WT[p] staged in LDS.
// C/D: col=lane&15, row=q*4+reg  [validated earlier rounds]
__global__ __launch_bounds__(256) void gemm_mfma_kernel(
    const unsigned short* __restrict__ hb, const unsigned short* __restrict__ WT_all,
    const float* __restrict__ al_all, const float* __restrict__ ar_all,
    unsigned short* __restrict__ featb_all, float* __restrict__ el_all,
    float* __restrict__ er_all) {
  __shared__ unsigned short Bs[128 * 128];   // 32 KB: whole WT[p]
  const int p = blockIdx.y;
  const unsigned short* WTp = WT_all + (size_t)p * 16384;
#pragma unroll
  for (int it = 0; it < 8; ++it)
    ((float4*)Bs)[it * 256 + threadIdx.x] = ((const float4*)WTp)[it * 256 + threadIdx.x];
  __syncthreads();

  const int wid = threadIdx.x >> 6, lane = threadIdx.x & 63;
  const int c = lane & 15, q = lane >> 4;
  const int tile = blockIdx.x * 4 + wid;       // 16-row tile; NN/16 = 6250 exact
  const int tc = tile < 6250 ? tile : 6249;    // clamp for safe loads; stores guarded

  f32x4 acc[8];
#pragma unroll
  for (int t = 0; t < 8; ++t) acc[t] = (f32x4){0.f, 0.f, 0.f, 0.f};

  const unsigned short* arow = hb + (size_t)(tc * 16 + c) * 128 + q * 8;
#pragma unroll
  for (int kc = 0; kc < 4; ++kc) {
    short8 a = *(const short8*)(arow + kc * 32);
#pragma unroll
    for (int t = 0; t < 8; ++t) {
      short8 b = *(const short8*)(Bs + (size_t)(t * 16 + c) * 128 + kc * 32 + q * 8);
      acc[t] = __builtin_amdgcn_mfma_f32_16x16x32_bf16(a, b, acc[t], 0, 0, 0);
    }
  }
  if (tile >= 6250) return;

  unsigned short* featb = featb_all + (size_t)p * NN * 128;
#pragma unroll
  for (int t = 0; t < 8; ++t)
#pragma unroll
    for (int i = 0; i < 4; ++i)
      featb[(size_t)(tc * 16 + q * 4 + i) * 128 + t * 16 + c] = f2bf(acc[t][i]);

  const float* al = al_all + p * 128;
  const float* ar = ar_all + p * 128;
  float alv[8], arv[8];
#pragma unroll
  for (int t = 0; t < 8; ++t) { alv[t] = al[t * 16 + c]; arv[t] = ar[t * 16 + c]; }
  float elp[4][4], erp[4][4];   // [i][hh]
#pragma unroll
  for (int i = 0; i < 4; ++i)
#pragma unroll
    for (int hh = 0; hh < 4; ++hh) {
      elp[i][hh] = acc[2 * hh][i] * alv[2 * hh] + acc[2 * hh + 1][i] * alv[2 * hh + 1];
      erp[i][hh] = acc[2 * hh][i] * arv[2 * hh] + acc[2 * hh + 1][i] * arv[2 * hh + 1];
    }
#pragma unroll
  for (int m = 1; m <= 8; m <<= 1)
#pragma unroll
    for (int i = 0; i < 4; ++i)
#pragma unroll
      for (int hh = 0; hh < 4; ++hh) {
        elp[i][hh] += __shfl_xor(elp[i][hh], m);
        erp[i][hh] += __shfl_xor(erp[i][hh], m);
      }
  if (c == 0) {
    float* el = el_all + (size_t)p * NN * 4;
    float* er = er_all + (size_t)p * NN * 4;
#pragma unroll
    for (int i = 0; i < 4; ++i) {
      int row = tc * 16 + q * 4 + i;
      *(float4*)(el + (size_t)row * 4) = make_float4(elp[i][0], elp[i][1], elp[i][2], elp[i][3]);
      *(float4*)(er + (size_t)row * 4) = make_float4(erp[i][0], erp[i][1], erp[i][2], erp[i][3]);
    }
  }
}

// ---------------- gather2: fused per-bucket edge sort + attention gather ----------------
// One block per (bucket of 256 dst nodes, path); 512 thr = 8 waves.
// Stage: gather this bucket's edges from the dense per-block pairs segments (binary
// search over the 196-entry cumulative), LDS-histogram by node, scan, sort into srt[].
// This replaces the old fillB kernel (which ran at 3 waves/CU) and eliminates the global
// elist write+read (~30 MB) and gather's elist/cnt loads.
// Gather: wave w handles nodes w, w+8, ... of the bucket; same wave-local two-pass
// attention gather as before (deferred normalization), edges sourced from LDS.
__global__ __launch_bounds__(512) void gather2_kernel(
    const unsigned short* __restrict__ featb_all, const float* __restrict__ el_all,
    const float* __restrict__ er_all, const int* __restrict__ cntA,
    const int* __restrict__ baseA, const int* __restrict__ pairs,
    const float* __restrict__ bias_all, unsigned short* __restrict__ zb) {
  __shared__ int scnt[NBLK];     // per fillA-block count for this bucket
  __shared__ int sbase[NBLK];    // per fillA-block base within its segment
  __shared__ int scum[NBLK];     // exclusive cumulative of scnt
  __shared__ int totE;
  __shared__ int hist[SLW];      // per-node degree
  __shared__ int start[SLW];     // per-node start in srt
  __shared__ int wcur[SLW];      // scatter cursor
  __shared__ int earr[EMAX];     // staged packed edges
  __shared__ int srt[EMAX];      // node-sorted src ids
  const int tid = threadIdx.x;
  const int p = blockIdx.y, sl = blockIdx.x;

  // 1. load per-block counts/bases for this bucket
  for (int b = tid; b < NBLK; b += 512) {
    scnt[b] = cntA[((size_t)p * NBLK + b) * SBK + sl];
    sbase[b] = baseA[((size_t)p * NBLK + b) * SBK + sl];
  }
  if (tid < SLW) hist[tid] = 0;
  __syncthreads();
  // 2. scan scnt -> scum (exclusive) + total
  if (tid < NBLK) scum[tid] = scnt[tid];
  __syncthreads();
  for (int off = 1; off < NBLK; off <<= 1) {
    int a = (tid < NBLK && tid >= off) ? scum[tid - off] : 0;
    __syncthreads();
    if (tid < NBLK) scum[tid] += a;
    __syncthreads();
  }
  if (tid == NBLK - 1) { int t = scum[NBLK - 1]; totE = t > EMAX ? EMAX : t; }
  int excl = (tid < NBLK) ? scum[tid] - scnt[tid] : 0;
  __syncthreads();
  if (tid < NBLK) scum[tid] = excl;
  __syncthreads();
  const int total = totE;
  // 3. stage edges + node histogram
  const int* prp = pairs + (size_t)p * NE;
  for (int e = tid; e < total; e += 512) {
    int lo = 0, hi = NBLK - 1;
    while (lo < hi) { int mid = (lo + hi + 1) >> 1; if (scum[mid] <= e) lo = mid; else hi = mid - 1; }
    int pk = prp[(size_t)lo * ECHUNK + sbase[lo] + (e - scum[lo])];
    earr[e] = pk;
    atomicAdd(&hist[pk >> 17], 1);
  }
  __syncthreads();
  // 4. scan hist -> start (exclusive); wcur = start
  if (tid < SLW) start[tid] = hist[tid];
  __syncthreads();
  for (int off = 1; off < SLW; off <<= 1) {
    int a = (tid < SLW && tid >= off) ? start[tid - off] : 0;
    __syncthreads();
    if (tid < SLW) start[tid] += a;
    __syncthreads();
  }
  if (tid < SLW) { int st = start[tid] - hist[tid]; start[tid] = st; wcur[tid] = st; }
  __syncthreads();
  // 5. sort into srt
  for (int e = tid; e < total; e += 512) {
    int pk = earr[e];
    int pos = atomicAdd(&wcur[pk >> 17], 1);
    srt[pos] = pk & 0x1FFFF;
  }
  __syncthreads();

  // 6. per-node gather (wave-local, deferred normalization)
  const unsigned short* featb = featb_all + (size_t)p * NN * 128;
  const float* el = el_all + (size_t)p * NN * 4;
  const int w = tid >> 6, lane = tid & 63;
  const int j16 = lane & 15, hgrp = lane >> 4;       // pass-1 coords
  const int sub = lane >> 4, c16 = lane & 15;        // pass-2 coords
  const int hh = c16 >> 2;
  for (int nl = w; nl < SLW; nl += 8) {
    int n = sl * SLW + nl;
    if (n >= NN) continue;
    int deg = hist[nl];
    int st = start[nl];
    float4 ern = *(const float4*)(er_all + (size_t)p * NN * 4 + (size_t)n * 4);
    const float ernh = hgrp == 0 ? ern.x : hgrp == 1 ? ern.y : hgrp == 2 ? ern.z : ern.w;
    float acc[8] = {0.f, 0.f, 0.f, 0.f, 0.f, 0.f, 0.f, 0.f};
    float dsum = 0.f;
    for (int b = 0; b < deg; b += 16) {
      int s = 0; float x = 0.f;
      int jj = b + j16;
      if (jj < deg) {
        s = srt[st + jj];
        float ev = el[(size_t)s * 4 + hgrp];
        float e = ev + ernh; e = fmaxf(e, 0.2f * e);
        x = __expf(e);
      }
      int bend = deg - b; bend = bend > 16 ? 16 : bend;
      for (int i = 0; i < bend; i += 8) {
        int j0 = i + sub, j1 = i + 4 + sub;          // pad edges have x=0,s=0
        int s0 = __shfl(s, j0);
        int s1 = __shfl(s, j1);
        float xv0 = __shfl(x, (hh << 4) | j0);
        float xv1 = __shfl(x, (hh << 4) | j1);
        short8 f0 = *(const short8*)(featb + (size_t)s0 * 128 + c16 * 8);
        short8 f1 = *(const short8*)(featb + (size_t)s1 * 128 + c16 * 8);
        dsum += xv0 + xv1;
#pragma unroll
        for (int k = 0; k < 8; ++k) acc[k] += xv0 * bf2f((unsigned short)f0[k]);
#pragma unroll
        for (int k = 0; k < 8; ++k) acc[k] += xv1 * bf2f((unsigned short)f1[k]);
      }
    }
    // reduce over the 4 sub-groups (lane bits 4,5)
    dsum += __shfl_xor(dsum, 16); dsum += __shfl_xor(dsum, 32);
#pragma unroll
    for (int k = 0; k < 8; ++k) {
      acc[k] += __shfl_xor(acc[k], 16);
      acc[k] += __shfl_xor(acc[k], 32);
    }
    if (sub == 0) {
      float rd = dsum > 0.f ? 1.f / dsum : 0.f;
      const float* bias = bias_all + p * 128 + c16 * 8;
      float4 b0 = *(const float4*)(bias);
      float4 b1 = *(const float4*)(bias + 4);
      short8 o;
      o[0] = f2bf(acc[0] * rd + b0.x); o[1] = f2bf(acc[1] * rd + b0.y);
      o[2] = f2bf(acc[2] * rd + b0.z); o[3] = f2bf(acc[3] * rd + b0.w);
      o[4] = f2bf(acc[4] * rd + b1.x); o[5] = f2bf(acc[5] * rd + b1.y);
      o[6] = f2bf(acc[6] * rd + b1.z); o[7] = f2bf(acc[7] * rd + b1.w);
      *(short8*)(zb + (size_t)n * (NP * 128) + p * 128 + c16 * 8) = o;
    }
  }
}

// ---------------- MFMA semantic scores, reduced in-kernel to s[3] ----------------
__global__ __launch_bounds__(256) void sem_mfma_kernel(
    const unsigned short* __restrict__ zb, const unsigned short* __restrict__ W1T,
    const float* __restrict__ b1, const float* __restrict__ w2,
    float* __restrict__ s) {
  __shared__ float red3[3];
  if (threadIdx.x < 3) red3[threadIdx.x] = 0.f;
  __syncthreads();
  const int wid = threadIdx.x >> 6, lane = threadIdx.x & 63;
  const int tile = blockIdx.x * 4 + wid;       // (NN*NP)/16 = 18750 exact
  const bool active = tile < 18750;
  const int tc = active ? tile : 18749;
  const int c = lane & 15, q = lane >> 4;
  f32x4 acc[4];
#pragma unroll
  for (int t = 0; t < 4; ++t) acc[t] = (f32x4){0.f, 0.f, 0.f, 0.f};

  const unsigned short* arow = zb + (size_t)(tc * 16 + c) * 128 + q * 8;
  const unsigned short* brow = W1T + (size_t)c * 128 + q * 8;
#pragma unroll
  for (int kc = 0; kc < 4; ++kc) {
    short8 a = *(const short8*)(arow + kc * 32);
#pragma unroll
    for (int t = 0; t < 4; ++t) {
      short8 b = *(const short8*)(brow + (size_t)t * 16 * 128 + kc * 32);
      acc[t] = __builtin_amdgcn_mfma_f32_16x16x32_bf16(a, b, acc[t], 0, 0, 0);
    }
  }
  float part[4] = {0.f, 0.f, 0.f, 0.f};
#pragma unroll
  for (int t = 0; t < 4; ++t) {
    float bb = b1[t * 16 + c], ww = w2[t * 16 + c];
#pragma unroll
    for (int i = 0; i < 4; ++i) part[i] += tanh_fast(acc[t][i] + bb) * ww;
  }
#pragma unroll
  for (int m = 1; m <= 8; m <<= 1)
#pragma unroll
    for (int i = 0; i < 4; ++i) part[i] += __shfl_xor(part[i], m);
  if (active && c == 0) {
#pragma unroll
    for (int i = 0; i < 4; ++i)
      atomicAdd(&red3[(tc * 16 + q * 4 + i) % 3], part[i]);
  }
  __syncthreads();
  if (threadIdx.x < 3) atomicAdd(&s[threadIdx.x], red3[threadIdx.x]);
}

// ---------------- final combine: beta = softmax(s/N) inline, out = sum_p beta[p]*z ------
__global__ __launch_bounds__(256) void final_kernel(
    const unsigned short* __restrict__ zb, const float* __restrict__ s,
    float* __restrict__ out) {
  int i = blockIdx.x * blockDim.x + threadIdx.x;   // NN*16 threads, 8 cols each
  if (i >= NN * 16) return;
  float w0 = s[0] * (1.f / NN), w1 = s[1] * (1.f / NN), w2c = s[2] * (1.f / NN);
  float m = fmaxf(w0, fmaxf(w1, w2c));
  float e0 = __expf(w0 - m), e1 = __expf(w1 - m), e2 = __expf(w2c - m);
  float inv = 1.f / (e0 + e1 + e2);
  float b0 = e0 * inv, b1 = e1 * inv, b2 = e2 * inv;
  int n = i >> 4, g = i & 15;
  const unsigned short* zr = zb + (size_t)n * (NP * 128) + g * 8;
  ushort4 u0a = *(const ushort4*)(zr);
  ushort4 u0b = *(const ushort4*)(zr + 4);
  ushort4 u1a = *(const ushort4*)(zr + 128);
  ushort4 u1b = *(const ushort4*)(zr + 132);
  ushort4 u2a = *(const ushort4*)(zr + 256);
  ushort4 u2b = *(const ushort4*)(zr + 260);
  float4 oa, ob;
  oa.x = b0 * bf2f(u0a.x) + b1 * bf2f(u1a.x) + b2 * bf2f(u2a.x);
  oa.y = b0 * bf2f(u0a.y) + b1 * bf2f(u1a.y) + b2 * bf2f(u2a.y);
  oa.z = b0 * bf2f(u0a.z) + b1 * bf2f(u1a.z) + b2 * bf2f(u2a.z);
  oa.w = b0 * bf2f(u0a.w) + b1 * bf2f(u1a.w) + b2 * bf2f(u2a.w);
  ob.x = b0 * bf2f(u0b.x) + b1 * bf2f(u1b.x) + b2 * bf2f(u2b.x);
  ob.y = b0 * bf2f(u0b.y) + b1 * bf2f(u1b.y) + b2 * bf2f(u2b.y);
  ob.z = b0 * bf2f(u0b.z) + b1 * bf2f(u1b.z) + b2 * bf2f(u2b.z);
  ob.w = b0 * bf2f(u0b.w) + b1 * bf2f(u1b.w) + b2 * bf2f(u2b.w);
  float* op = out + (size_t)n * 128 + g * 8;
  *(float4*)op = oa;
  *(float4*)(op + 4) = ob;
}

extern "C" void kernel_launch(void* const* d_in, const int* in_sizes, int n_in,
                              void* d_out, int out_size, void* d_ws, size_t ws_size,
                              hipStream_t stream) {
  const float* h    = (const float*)d_in[0];
  const int*   esrc = (const int*)d_in[1];
  const int*   edst = (const int*)d_in[2];
  const float* W    = (const float*)d_in[3];
  const float* al   = (const float*)d_in[4];
  const float* ar   = (const float*)d_in[5];
  const float* bias = (const float*)d_in[6];
  const float* w1   = (const float*)d_in[7];
  const float* b1   = (const float*)d_in[8];
  const float* w2   = (const float*)d_in[9];
  float* out = (float*)d_out;

  // workspace layout (~196 MiB, no aliasing needed)
  unsigned short* zb    = (unsigned short*)d_ws;       // 38,400,000 bf16 = 76.8 MB
  unsigned short* featb = zb + (size_t)38400000;       // 38,400,000 bf16 (3 paths)
  unsigned short* WT    = featb + (size_t)38400000;    // 49,152 bf16
  unsigned short* W1T   = WT + 49152;                  // 8,192 bf16
  float* el   = (float*)(W1T + 8192);                  // 3*NN*4
  float* er   = el + (size_t)NP * NN * 4;              // 3*NN*4
  float* s    = er + (size_t)NP * NN * 4;              // 16
  int* cntA  = (int*)(s + 16);                         // NP*NBLK*SBK = 301,056 ints
  int* baseA = cntA + (size_t)NP * NBLK * SBK;         // same
  int* pairs = baseA + (size_t)NP * NBLK * SBK;        // NP*NE ints = 9.6 MB
  unsigned short* hb = (unsigned short*)(pairs + (size_t)NP * NE);  // NN*128 bf16 = 25.6 MB

  prep_fill_kernel<<<12500 + NP * NBLK, 256, 0, stream>>>(
      h, W, w1, esrc, edst, hb, WT, W1T, s, cntA, baseA, pairs);

  dim3 gemmGrid(NN / 64 + 1, NP);                      // 1563 x 3 (tiles clamped in-kernel)
  gemm_mfma_kernel<<<gemmGrid, 256, 0, stream>>>(hb, WT, al, ar, featb, el, er);

  dim3 g2Grid(GB, NP);                                 // 391 x 3, 512 thr
  gather2_kernel<<<g2Grid, 512, 0, stream>>>(featb, el, er, cntA, baseA, pairs, bias, zb);

  sem_mfma_kernel<<<(18750 + 3) / 4, 256, 0, stream>>>(zb, W1T, b1, w2, s);
  final_kernel<<<(NN * 16 + 255) / 256, 256, 0, stream>>>(zb, s, out);
}

// Round 5
// 457.505 us; speedup vs baseline: 1.0376x; 1.0376x over previous
//
#include <hip/hip_runtime.h>
#include <hip/hip_bf16.h>
#include <math.h>

// Problem constants (from reference)
#define NN 100000      // nodes
#define NP 3           // metapaths
#define NE 800000      // edges per path
#define NH 4           // heads
#define ND 32          // dim per head
#define HD 128         // H*D
#define NHID 64        // semantic hidden

// fill/gather geometry
#define SLW 256        // nodes per bucket (pow2: sl = d>>8, dl = d&255)
#define SBK 512        // bucket slots in fillA hist (>= GB; rest stay empty)
#define GB 391         // used buckets = ceil(NN/SLW)
#define NBLK 196       // fillA blocks per path = ceil(NE/4096)
#define ECHUNK 4096    // edges per fillA block
#define EPT 16         // edges per thread in fillA (256 thr)
#define EMAX 2368      // per-bucket edge cap: mean 2048, sigma 45 -> +7.1 sigma

typedef __attribute__((ext_vector_type(8))) short short8;
typedef __attribute__((ext_vector_type(4))) float f32x4;

__device__ __forceinline__ unsigned short f2bf(float f) {
  union { float f; unsigned int u; } v; v.f = f;
  unsigned int r = v.u + 0x7FFFu + ((v.u >> 16) & 1u);   // round-to-nearest-even
  return (unsigned short)(r >> 16);
}
__device__ __forceinline__ float bf2f(unsigned short u) {
  return __uint_as_float(((unsigned int)u) << 16);
}
__device__ __forceinline__ float tanh_fast(float x) {
  return 1.f - 2.f / (1.f + __expf(2.f * x));   // saturates correctly
}

// ---------------- prep + fillA fused (unchanged from R4, validated) ----------------
__global__ __launch_bounds__(256) void prep_fill_kernel(
    const float* __restrict__ h, const float* __restrict__ W, const float* __restrict__ W1,
    const int* __restrict__ src_all, const int* __restrict__ dst_all,
    unsigned short* __restrict__ hb, unsigned short* __restrict__ WT,
    unsigned short* __restrict__ W1T, float* __restrict__ s,
    int* __restrict__ cntA, int* __restrict__ baseA, int* __restrict__ pairs) {
  __shared__ int hist[SBK];
  __shared__ int scanb[SBK];
  const int tid = threadIdx.x;
  const int bx = blockIdx.x;
  if (bx < 12500) {
    int i = bx * 256 + tid;
    if (i < NN * 32) {                       // cast h, 4 elems per thread
      float4 v = ((const float4*)h)[i];
      ushort4 o;
      o.x = f2bf(v.x); o.y = f2bf(v.y); o.z = f2bf(v.z); o.w = f2bf(v.w);
      ((ushort4*)hb)[i] = o;
    }
    if (i < NP * 128 * 128) {                // WT[p][n][k] = W[p][k][n]
      int p = i >> 14, r = i & 16383, n = r >> 7, k = r & 127;
      WT[i] = f2bf(W[(size_t)p * 16384 + k * 128 + n]);
    }
    if (i < NHID * 128) {                    // W1T[n][k] = W1[k][n]
      int n = i >> 7, k = i & 127;
      W1T[i] = f2bf(W1[(size_t)k * NHID + n]);
    }
    if (i < 4) s[i] = 0.f;
    return;
  }
  // ---- fillA: per-block-exclusive counting compaction (dense packed writes) ----
  const int b2 = bx - 12500;
  const int p = b2 / NBLK, blk = b2 % NBLK;
  const int* dstp = dst_all + (size_t)p * NE;
  const int* srcp = src_all + (size_t)p * NE;
  hist[tid] = 0; hist[tid + 256] = 0;
  __syncthreads();
  int dv[EPT], sv[EPT];
#pragma unroll
  for (int k = 0; k < EPT; ++k) {
    int e = blk * ECHUNK + k * 256 + tid;
    dv[k] = -1; sv[k] = 0;
    if (e < NE) {
      dv[k] = __builtin_nontemporal_load(dstp + e);
      sv[k] = __builtin_nontemporal_load(srcp + e);
    }
    if (dv[k] >= 0) atomicAdd(&hist[(unsigned)dv[k] >> 8], 1);
  }
  __syncthreads();
  // inclusive scan of hist (512 entries, 2 per thread, Hillis-Steele)
  scanb[tid] = hist[tid]; scanb[tid + 256] = hist[tid + 256];
  __syncthreads();
  for (int off = 1; off < SBK; off <<= 1) {
    int a0 = (tid >= off) ? scanb[tid - off] : 0;
    int a1 = scanb[tid + 256 - off];          // tid+256 >= off always (off<=256)
    __syncthreads();
    scanb[tid] += a0; scanb[tid + 256] += a1;
    __syncthreads();
  }
  int c0 = hist[tid], c1 = hist[tid + 256];
  int b0 = scanb[tid] - c0, b1 = scanb[tid + 256] - c1;
  int* cA = cntA + ((size_t)p * NBLK + blk) * SBK;
  int* bA = baseA + ((size_t)p * NBLK + blk) * SBK;
  cA[tid] = c0; cA[tid + 256] = c1;
  bA[tid] = b0; bA[tid + 256] = b1;
  __syncthreads();
  scanb[tid] = b0; scanb[tid + 256] = b1;
  hist[tid] = 0; hist[tid + 256] = 0;
  __syncthreads();
  int* prp = pairs + (size_t)p * NE + (size_t)blk * ECHUNK;
#pragma unroll
  for (int k = 0; k < EPT; ++k) {
    if (dv[k] >= 0) {
      int sl = (unsigned)dv[k] >> 8;
      int pos = scanb[sl] + atomicAdd(&hist[sl], 1);
      prp[pos] = ((dv[k] & 255) << 17) | sv[k];    // src < 2^17
    }
  }
}

// ---------------- MFMA feature GEMM (all paths) + fused el/er (unchanged) ----------------
__global__ __launch_bounds__(256) void gemm_mfma_kernel(
    const unsigned short* __restrict__ hb, const unsigned short* __restrict__ WT_all,
    const float* __restrict__ al_all, const float* __restrict__ ar_all,
    unsigned short* __restrict__ featb_all, float* __restrict__ el_all,
    float* __restrict__ er_all) {
  __shared__ unsigned short Bs[128 * 128];   // 32 KB: whole WT[p]
  const int p = blockIdx.y;
  const unsigned short* WTp = WT_all + (size_t)p * 16384;
#pragma unroll
  for (int it = 0; it < 8; ++it)
    ((float4*)Bs)[it * 256 + threadIdx.x] = ((const float4*)WTp)[it * 256 + threadIdx.x];
  __syncthreads();

  const int wid = threadIdx.x >> 6, lane = threadIdx.x & 63;
  const int c = lane & 15, q = lane >> 4;
  const int tile = blockIdx.x * 4 + wid;       // 16-row tile; NN/16 = 6250 exact
  const int tc = tile < 6250 ? tile : 6249;    // clamp for safe loads; stores guarded

  f32x4 acc[8];
#pragma unroll
  for (int t = 0; t < 8; ++t) acc[t] = (f32x4){0.f, 0.f, 0.f, 0.f};

  const unsigned short* arow = hb + (size_t)(tc * 16 + c) * 128 + q * 8;
#pragma unroll
  for (int kc = 0; kc < 4; ++kc) {
    short8 a = *(const short8*)(arow + kc * 32);
#pragma unroll
    for (int t = 0; t < 8; ++t) {
      short8 b = *(const short8*)(Bs + (size_t)(t * 16 + c) * 128 + kc * 32 + q * 8);
      acc[t] = __builtin_amdgcn_mfma_f32_16x16x32_bf16(a, b, acc[t], 0, 0, 0);
    }
  }
  if (tile >= 6250) return;

  unsigned short* featb = featb_all + (size_t)p * NN * 128;
#pragma unroll
  for (int t = 0; t < 8; ++t)
#pragma unroll
    for (int i = 0; i < 4; ++i)
      featb[(size_t)(tc * 16 + q * 4 + i) * 128 + t * 16 + c] = f2bf(acc[t][i]);

  const float* al = al_all + p * 128;
  const float* ar = ar_all + p * 128;
  float alv[8], arv[8];
#pragma unroll
  for (int t = 0; t < 8; ++t) { alv[t] = al[t * 16 + c]; arv[t] = ar[t * 16 + c]; }
  float elp[4][4], erp[4][4];   // [i][hh]
#pragma unroll
  for (int i = 0; i < 4; ++i)
#pragma unroll
    for (int hh = 0; hh < 4; ++hh) {
      elp[i][hh] = acc[2 * hh][i] * alv[2 * hh] + acc[2 * hh + 1][i] * alv[2 * hh + 1];
      erp[i][hh] = acc[2 * hh][i] * arv[2 * hh] + acc[2 * hh + 1][i] * arv[2 * hh + 1];
    }
#pragma unroll
  for (int m = 1; m <= 8; m <<= 1)
#pragma unroll
    for (int i = 0; i < 4; ++i)
#pragma unroll
      for (int hh = 0; hh < 4; ++hh) {
        elp[i][hh] += __shfl_xor(elp[i][hh], m);
        erp[i][hh] += __shfl_xor(erp[i][hh], m);
      }
  if (c == 0) {
    float* el = el_all + (size_t)p * NN * 4;
    float* er = er_all + (size_t)p * NN * 4;
#pragma unroll
    for (int i = 0; i < 4; ++i) {
      int row = tc * 16 + q * 4 + i;
      *(float4*)(el + (size_t)row * 4) = make_float4(elp[i][0], elp[i][1], elp[i][2], elp[i][3]);
      *(float4*)(er + (size_t)row * 4) = make_float4(erp[i][0], erp[i][1], erp[i][2], erp[i][3]);
    }
  }
}

// ---------------- fillB2a: per-bucket sort into dense global CSR ----------------
// R4 post-mortem: doing this INSIDE gather serialized 8 waves behind ~10 barriers and
// dropped occupancy 82->58%. As a standalone small kernel (391x3 blocks, 512 thr) the
// staging cost overlaps across blocks. Logic = R4 gather2 steps 1-5 (validated).
// Output: srtpk[bucket-dense] (full pk: dl<<17|src), rowidx[n]=(abs start, deg), btot.
__global__ __launch_bounds__(512) void fillB2a_kernel(
    const int* __restrict__ cntA, const int* __restrict__ baseA,
    const int* __restrict__ pairs, int* __restrict__ srtpk,
    int2* __restrict__ rowidx, int* __restrict__ btot) {
  __shared__ int scnt[NBLK];
  __shared__ int sbase[NBLK];
  __shared__ int scum[NBLK];
  __shared__ int totE;
  __shared__ int hist[SLW];
  __shared__ int start[SLW];
  __shared__ int wcur[SLW];
  __shared__ int earr[EMAX];
  const int tid = threadIdx.x;
  const int p = blockIdx.y, sl = blockIdx.x;
  const size_t base = ((size_t)p * GB + sl) * EMAX;

  for (int b = tid; b < NBLK; b += 512) {
    scnt[b] = cntA[((size_t)p * NBLK + b) * SBK + sl];
    sbase[b] = baseA[((size_t)p * NBLK + b) * SBK + sl];
  }
  if (tid < SLW) hist[tid] = 0;
  __syncthreads();
  if (tid < NBLK) scum[tid] = scnt[tid];
  __syncthreads();
  for (int off = 1; off < NBLK; off <<= 1) {
    int a = (tid < NBLK && tid >= off) ? scum[tid - off] : 0;
    __syncthreads();
    if (tid < NBLK) scum[tid] += a;
    __syncthreads();
  }
  if (tid == NBLK - 1) { int t = scum[NBLK - 1]; totE = t > EMAX ? EMAX : t; }
  int excl = (tid < NBLK) ? scum[tid] - scnt[tid] : 0;
  __syncthreads();
  if (tid < NBLK) scum[tid] = excl;
  __syncthreads();
  const int total = totE;
  // stage edges + node histogram
  const int* prp = pairs + (size_t)p * NE;
  for (int e = tid; e < total; e += 512) {
    int lo = 0, hi = NBLK - 1;
    while (lo < hi) { int mid = (lo + hi + 1) >> 1; if (scum[mid] <= e) lo = mid; else hi = mid - 1; }
    int pk = prp[(size_t)lo * ECHUNK + sbase[lo] + (e - scum[lo])];
    earr[e] = pk;
    atomicAdd(&hist[pk >> 17], 1);
  }
  __syncthreads();
  // scan hist -> start (exclusive); wcur = start
  if (tid < SLW) start[tid] = hist[tid];
  __syncthreads();
  for (int off = 1; off < SLW; off <<= 1) {
    int a = (tid < SLW && tid >= off) ? start[tid - off] : 0;
    __syncthreads();
    if (tid < SLW) start[tid] += a;
    __syncthreads();
  }
  if (tid < SLW) { int st = start[tid] - hist[tid]; start[tid] = st; wcur[tid] = st; }
  __syncthreads();
  // sort into global srtpk (dense ~9.3KB region per bucket, fully populated -> clean WB)
  for (int e = tid; e < total; e += 512) {
    int pk = earr[e];
    int pos = atomicAdd(&wcur[pk >> 17], 1);
    srtpk[base + pos] = pk;
  }
  // per-node CSR entry (start/hist stable since their last barrier)
  if (tid < SLW) {
    int n = sl * SLW + tid;
    if (n < NN) rowidx[(size_t)p * NN + n] = make_int2((int)(base + start[tid]), hist[tid]);
  }
  if (tid == 0) btot[p * GB + sl] = total;
}

// ---------------- fillB2b: edge-parallel x precompute ----------------
// Pulls the scattered el[src] gather + exp OFF gather's critical path: fully parallel
// across 2.4M edges (latency-tolerant), writes dense coalesced xs (float4/edge).
__global__ __launch_bounds__(256) void fillB2b_kernel(
    const int* __restrict__ srtpk, const int* __restrict__ btot,
    const float* __restrict__ el_all, const float* __restrict__ er_all,
    float4* __restrict__ xs) {
  const int p = blockIdx.y, sl = blockIdx.x;
  const int total = btot[p * GB + sl];
  const size_t base = ((size_t)p * GB + sl) * EMAX;
  const float* el = el_all + (size_t)p * NN * 4;
  const float* er = er_all + (size_t)p * NN * 4;
  for (int i = threadIdx.x; i < total; i += 256) {
    int pk = srtpk[base + i];
    int src = pk & 0x1FFFF, dl = pk >> 17;
    int n = sl * SLW + dl;
    float4 ev = *(const float4*)(el + (size_t)src * 4);
    float4 rv = *(const float4*)(er + (size_t)n * 4);
    float4 x;
    float e0 = ev.x + rv.x; e0 = fmaxf(e0, 0.2f * e0); x.x = __expf(e0);
    float e1 = ev.y + rv.y; e1 = fmaxf(e1, 0.2f * e1); x.y = __expf(e1);
    float e2 = ev.z + rv.z; e2 = fmaxf(e2, 0.2f * e2); x.z = __expf(e2);
    float e3 = ev.w + rv.w; e3 = fmaxf(e3, 0.2f * e3); x.w = __expf(e3);
    xs[base + i] = x;
  }
}

// ---------------- gather3: slim consumer (one scattered round-trip) ----------------
// Per node: dense 8B rowidx -> dense coalesced srtpk/xs loads (no exp, no scattered el)
// -> shfl -> scattered feat load -> FMA. Deferred normalization as before.
__global__ __launch_bounds__(256) void gather3_kernel(
    const unsigned short* __restrict__ featb_all, const int* __restrict__ srtpk,
    const float* __restrict__ xs, const int2* __restrict__ rowidx,
    const float* __restrict__ bias_all, unsigned short* __restrict__ zb) {
  const int p = blockIdx.y;
  const unsigned short* featb = featb_all + (size_t)p * NN * 128;
  const int wid = threadIdx.x >> 6;
  const int lane = threadIdx.x & 63;
  const int n = blockIdx.x * 4 + wid;        // NN % 4 == 0
  int2 rd = rowidx[(size_t)p * NN + n];
  const int rbase = rd.x, deg = rd.y;

  const int j16 = lane & 15, hgrp = lane >> 4;       // pass-1 coords
  const int sub = lane >> 4, c16 = lane & 15;        // pass-2 coords
  const int hh = c16 >> 2;

  float acc[8] = {0.f, 0.f, 0.f, 0.f, 0.f, 0.f, 0.f, 0.f};
  float dsum = 0.f;

  for (int b = 0; b < deg; b += 16) {
    // pass 1: lane (hgrp,j16) grabs x for edge b+j16, head hgrp — dense coalesced loads
    int s = 0; float x = 0.f;
    int jj = b + j16;
    if (jj < deg) {
      int idx = rbase + jj;
      s = srtpk[idx] & 0x1FFFF;
      x = xs[(size_t)idx * 4 + hgrp];
    }
    // pass 2: quarter-wave per edge, 8 edges per sub-iteration, 16B/lane feat loads
    int bend = deg - b; bend = bend > 16 ? 16 : bend;
    for (int i = 0; i < bend; i += 8) {
      int j0 = i + sub, j1 = i + 4 + sub;            // pad edges have x=0,s=0
      int s0 = __shfl(s, j0);
      int s1 = __shfl(s, j1);
      float xv0 = __shfl(x, (hh << 4) | j0);
      float xv1 = __shfl(x, (hh << 4) | j1);
      short8 f0 = *(const short8*)(featb + (size_t)s0 * 128 + c16 * 8);
      short8 f1 = *(const short8*)(featb + (size_t)s1 * 128 + c16 * 8);
      dsum += xv0 + xv1;
#pragma unroll
      for (int k = 0; k < 8; ++k) acc[k] += xv0 * bf2f((unsigned short)f0[k]);
#pragma unroll
      for (int k = 0; k < 8; ++k) acc[k] += xv1 * bf2f((unsigned short)f1[k]);
    }
  }
  // reduce over the 4 sub-groups (lane bits 4,5)
  dsum += __shfl_xor(dsum, 16); dsum += __shfl_xor(dsum, 32);
#pragma unroll
  for (int k = 0; k < 8; ++k) {
    acc[k] += __shfl_xor(acc[k], 16);
    acc[k] += __shfl_xor(acc[k], 32);
  }
  if (sub == 0) {
    float rdn = dsum > 0.f ? 1.f / dsum : 0.f;
    const float* bias = bias_all + p * 128 + c16 * 8;
    float4 b0 = *(const float4*)(bias);
    float4 b1 = *(const float4*)(bias + 4);
    short8 o;
    o[0] = f2bf(acc[0] * rdn + b0.x); o[1] = f2bf(acc[1] * rdn + b0.y);
    o[2] = f2bf(acc[2] * rdn + b0.z); o[3] = f2bf(acc[3] * rdn + b0.w);
    o[4] = f2bf(acc[4] * rdn + b1.x); o[5] = f2bf(acc[5] * rdn + b1.y);
    o[6] = f2bf(acc[6] * rdn + b1.z); o[7] = f2bf(acc[7] * rdn + b1.w);
    *(short8*)(zb + (size_t)n * (NP * 128) + p * 128 + c16 * 8) = o;
  }
}

// ---------------- MFMA semantic scores, reduced in-kernel to s[3] (unchanged) ----------
__global__ __launch_bounds__(256) void sem_mfma_kernel(
    const unsigned short* __restrict__ zb, const unsigned short* __restrict__ W1T,
    const float* __restrict__ b1, const float* __restrict__ w2,
    float* __restrict__ s) {
  __shared__ float red3[3];
  if (threadIdx.x < 3) red3[threadIdx.x] = 0.f;
  __syncthreads();
  const int wid = threadIdx.x >> 6, lane = threadIdx.x & 63;
  const int tile = blockIdx.x * 4 + wid;       // (NN*NP)/16 = 18750 exact
  const bool active = tile < 18750;
  const int tc = active ? tile : 18749;
  const int c = lane & 15, q = lane >> 4;
  f32x4 acc[4];
#pragma unroll
  for (int t = 0; t < 4; ++t) acc[t] = (f32x4){0.f, 0.f, 0.f, 0.f};

  const unsigned short* arow = zb + (size_t)(tc * 16 + c) * 128 + q * 8;
  const unsigned short* brow = W1T + (size_t)c * 128 + q * 8;
#pragma unroll
  for (int kc = 0; kc < 4; ++kc) {
    short8 a = *(const short8*)(arow + kc * 32);
#pragma unroll
    for (int t = 0; t < 4; ++t) {
      short8 b = *(const short8*)(brow + (size_t)t * 16 * 128 + kc * 32);
      acc[t] = __builtin_amdgcn_mfma_f32_16x16x32_bf16(a, b, acc[t], 0, 0, 0);
    }
  }
  float part[4] = {0.f, 0.f, 0.f, 0.f};
#pragma unroll
  for (int t = 0; t < 4; ++t) {
    float bb = b1[t * 16 + c], ww = w2[t * 16 + c];
#pragma unroll
    for (int i = 0; i < 4; ++i) part[i] += tanh_fast(acc[t][i] + bb) * ww;
  }
#pragma unroll
  for (int m = 1; m <= 8; m <<= 1)
#pragma unroll
    for (int i = 0; i < 4; ++i) part[i] += __shfl_xor(part[i], m);
  if (active && c == 0) {
#pragma unroll
    for (int i = 0; i < 4; ++i)
      atomicAdd(&red3[(tc * 16 + q * 4 + i) % 3], part[i]);
  }
  __syncthreads();
  if (threadIdx.x < 3) atomicAdd(&s[threadIdx.x], red3[threadIdx.x]);
}

// ---------------- final combine (unchanged) ----------------
__global__ __launch_bounds__(256) void final_kernel(
    const unsigned short* __restrict__ zb, const float* __restrict__ s,
    float* __restrict__ out) {
  int i = blockIdx.x * blockDim.x + threadIdx.x;   // NN*16 threads, 8 cols each
  if (i >= NN * 16) return;
  float w0 = s[0] * (1.f / NN), w1 = s[1] * (1.f / NN), w2c = s[2] * (1.f / NN);
  float m = fmaxf(w0, fmaxf(w1, w2c));
  float e0 = __expf(w0 - m), e1 = __expf(w1 - m), e2 = __expf(w2c - m);
  float inv = 1.f / (e0 + e1 + e2);
  float b0 = e0 * inv, b1 = e1 * inv, b2 = e2 * inv;
  int n = i >> 4, g = i & 15;
  const unsigned short* zr = zb + (size_t)n * (NP * 128) + g * 8;
  ushort4 u0a = *(const ushort4*)(zr);
  ushort4 u0b = *(const ushort4*)(zr + 4);
  ushort4 u1a = *(const ushort4*)(zr + 128);
  ushort4 u1b = *(const ushort4*)(zr + 132);
  ushort4 u2a = *(const ushort4*)(zr + 256);
  ushort4 u2b = *(const ushort4*)(zr + 260);
  float4 oa, ob;
  oa.x = b0 * bf2f(u0a.x) + b1 * bf2f(u1a.x) + b2 * bf2f(u2a.x);
  oa.y = b0 * bf2f(u0a.y) + b1 * bf2f(u1a.y) + b2 * bf2f(u2a.y);
  oa.z = b0 * bf2f(u0a.z) + b1 * bf2f(u1a.z) + b2 * bf2f(u2a.z);
  oa.w = b0 * bf2f(u0a.w) + b1 * bf2f(u1a.w) + b2 * bf2f(u2a.w);
  ob.x = b0 * bf2f(u0b.x) + b1 * bf2f(u1b.x) + b2 * bf2f(u2b.x);
  ob.y = b0 * bf2f(u0b.y) + b1 * bf2f(u1b.y) + b2 * bf2f(u2b.y);
  ob.z = b0 * bf2f(u0b.z) + b1 * bf2f(u1b.z) + b2 * bf2f(u2b.z);
  ob.w = b0 * bf2f(u0b.w) + b1 * bf2f(u1b.w) + b2 * bf2f(u2b.w);
  float* op = out + (size_t)n * 128 + g * 8;
  *(float4*)op = oa;
  *(float4*)(op + 4) = ob;
}

extern "C" void kernel_launch(void* const* d_in, const int* in_sizes, int n_in,
                              void* d_out, int out_size, void* d_ws, size_t ws_size,
                              hipStream_t stream) {
  const float* h    = (const float*)d_in[0];
  const int*   esrc = (const int*)d_in[1];
  const int*   edst = (const int*)d_in[2];
  const float* W    = (const float*)d_in[3];
  const float* al   = (const float*)d_in[4];
  const float* ar   = (const float*)d_in[5];
  const float* bias = (const float*)d_in[6];
  const float* w1   = (const float*)d_in[7];
  const float* b1   = (const float*)d_in[8];
  const float* w2   = (const float*)d_in[9];
  float* out = (float*)d_out;

  // workspace layout: 221.3 MB <= 222.1 MB proven (R2).
  // Region X (xs, 44.4 MB) OVERLAYS cntA+baseA+pairs (dead after fillB2a) and hb (dead
  // after gemm); fillB2b (the xs writer) runs after both — stream-ordered, safe.
  unsigned short* zb    = (unsigned short*)d_ws;       // 38,400,000 bf16 = 76.8 MB
  unsigned short* featb = zb + (size_t)38400000;       // 38,400,000 bf16
  unsigned short* WT    = featb + (size_t)38400000;    // 49,152 bf16
  unsigned short* W1T   = WT + 49152;                  // 8,192 bf16
  float* el   = (float*)(W1T + 8192);                  // 1,200,000 f
  float* er   = el + (size_t)1200000;                  // 1,200,000 f
  float* s    = er + (size_t)1200000;                  // 16 f
  int2* rowidx = (int2*)(s + 16);                      // NP*NN int2 = 2.4 MB
  int* btot  = (int*)(rowidx + (size_t)NP * NN);       // 1280 ints
  int* srtpk = btot + 1280;                            // NP*GB*EMAX = 2,777,664 ints
  // ---- region X ----
  int* cntA  = srtpk + (size_t)NP * GB * EMAX;         // 301,056 ints
  int* baseA = cntA + (size_t)NP * NBLK * SBK;         // 301,056 ints
  int* pairs = baseA + (size_t)NP * NBLK * SBK;        // 2,400,000 ints
  unsigned short* hb = (unsigned short*)(pairs + (size_t)NP * NE);  // 25.6 MB
  float* xs = (float*)cntA;                            // float4 view, 44.44 MB overlay

  prep_fill_kernel<<<12500 + NP * NBLK, 256, 0, stream>>>(
      h, W, w1, esrc, edst, hb, WT, W1T, s, cntA, baseA, pairs);

  dim3 bGrid(GB, NP);                                  // 391 x 3
  fillB2a_kernel<<<bGrid, 512, 0, stream>>>(cntA, baseA, pairs, srtpk, rowidx, btot);

  dim3 gemmGrid(NN / 64 + 1, NP);                      // 1563 x 3 (tiles clamped in-kernel)
  gemm_mfma_kernel<<<gemmGrid, 256, 0, stream>>>(hb, WT, al, ar, featb, el, er);

  fillB2b_kernel<<<bGrid, 256, 0, stream>>>(srtpk, btot, el, er, (float4*)xs);

  dim3 gatherGrid(NN / 4, NP);
  gather3_kernel<<<gatherGrid, 256, 0, stream>>>(featb, srtpk, xs, rowidx, bias, zb);

  sem_mfma_kernel<<<(18750 + 3) / 4, 256, 0, stream>>>(zb, W1T, b1, w2, s);
  final_kernel<<<(NN * 16 + 255) / 256, 256, 0, stream>>>(zb, s, out);
}

// Round 6
// 446.288 us; speedup vs baseline: 1.0637x; 1.0251x over previous
//
#include <hip/hip_runtime.h>
#include <hip/hip_bf16.h>
#include <math.h>

// Problem constants (from reference)
#define NN 100000      // nodes
#define NP 3           // metapaths
#define NE 800000      // edges per path
#define NH 4           // heads
#define ND 32          // dim per head
#define HD 128         // H*D
#define NHID 64        // semantic hidden

// fill/gather geometry
#define SLW 256        // nodes per bucket (pow2: sl = d>>8, dl = d&255)
#define SBK 512        // bucket slots in fillA hist (>= GB; rest stay empty)
#define GB 391         // used buckets = ceil(NN/SLW)
#define NBLK 196       // fillA blocks per path = ceil(NE/4096)
#define ECHUNK 4096    // edges per fillA block
#define EPT 16         // edges per thread in fillA (256 thr)
#define EMAX 2368      // per-bucket edge cap: mean 2048, sigma 45 -> +7.1 sigma

typedef __attribute__((ext_vector_type(8))) short short8;
typedef __attribute__((ext_vector_type(4))) float f32x4;

__device__ __forceinline__ unsigned short f2bf(float f) {
  union { float f; unsigned int u; } v; v.f = f;
  unsigned int r = v.u + 0x7FFFu + ((v.u >> 16) & 1u);   // round-to-nearest-even
  return (unsigned short)(r >> 16);
}
__device__ __forceinline__ float bf2f(unsigned short u) {
  return __uint_as_float(((unsigned int)u) << 16);
}
__device__ __forceinline__ float tanh_fast(float x) {
  return 1.f - 2.f / (1.f + __expf(2.f * x));   // saturates correctly
}

// ---------------- prep + fillA fused (unchanged, validated) ----------------
__global__ __launch_bounds__(256) void prep_fill_kernel(
    const float* __restrict__ h, const float* __restrict__ W, const float* __restrict__ W1,
    const int* __restrict__ src_all, const int* __restrict__ dst_all,
    unsigned short* __restrict__ hb, unsigned short* __restrict__ WT,
    unsigned short* __restrict__ W1T, float* __restrict__ s,
    int* __restrict__ cntA, int* __restrict__ baseA, int* __restrict__ pairs) {
  __shared__ int hist[SBK];
  __shared__ int scanb[SBK];
  const int tid = threadIdx.x;
  const int bx = blockIdx.x;
  if (bx < 12500) {
    int i = bx * 256 + tid;
    if (i < NN * 32) {                       // cast h, 4 elems per thread
      float4 v = ((const float4*)h)[i];
      ushort4 o;
      o.x = f2bf(v.x); o.y = f2bf(v.y); o.z = f2bf(v.z); o.w = f2bf(v.w);
      ((ushort4*)hb)[i] = o;
    }
    if (i < NP * 128 * 128) {                // WT[p][n][k] = W[p][k][n]
      int p = i >> 14, r = i & 16383, n = r >> 7, k = r & 127;
      WT[i] = f2bf(W[(size_t)p * 16384 + k * 128 + n]);
    }
    if (i < NHID * 128) {                    // W1T[n][k] = W1[k][n]
      int n = i >> 7, k = i & 127;
      W1T[i] = f2bf(W1[(size_t)k * NHID + n]);
    }
    if (i < 4) s[i] = 0.f;
    return;
  }
  // ---- fillA: per-block-exclusive counting compaction (dense packed writes) ----
  const int b2 = bx - 12500;
  const int p = b2 / NBLK, blk = b2 % NBLK;
  const int* dstp = dst_all + (size_t)p * NE;
  const int* srcp = src_all + (size_t)p * NE;
  hist[tid] = 0; hist[tid + 256] = 0;
  __syncthreads();
  int dv[EPT], sv[EPT];
#pragma unroll
  for (int k = 0; k < EPT; ++k) {
    int e = blk * ECHUNK + k * 256 + tid;
    dv[k] = -1; sv[k] = 0;
    if (e < NE) {
      dv[k] = __builtin_nontemporal_load(dstp + e);
      sv[k] = __builtin_nontemporal_load(srcp + e);
    }
    if (dv[k] >= 0) atomicAdd(&hist[(unsigned)dv[k] >> 8], 1);
  }
  __syncthreads();
  // inclusive scan of hist (512 entries, 2 per thread, Hillis-Steele)
  scanb[tid] = hist[tid]; scanb[tid + 256] = hist[tid + 256];
  __syncthreads();
  for (int off = 1; off < SBK; off <<= 1) {
    int a0 = (tid >= off) ? scanb[tid - off] : 0;
    int a1 = scanb[tid + 256 - off];          // tid+256 >= off always (off<=256)
    __syncthreads();
    scanb[tid] += a0; scanb[tid + 256] += a1;
    __syncthreads();
  }
  int c0 = hist[tid], c1 = hist[tid + 256];
  int b0 = scanb[tid] - c0, b1 = scanb[tid + 256] - c1;
  int* cA = cntA + ((size_t)p * NBLK + blk) * SBK;
  int* bA = baseA + ((size_t)p * NBLK + blk) * SBK;
  cA[tid] = c0; cA[tid + 256] = c1;
  bA[tid] = b0; bA[tid + 256] = b1;
  __syncthreads();
  scanb[tid] = b0; scanb[tid + 256] = b1;
  hist[tid] = 0; hist[tid + 256] = 0;
  __syncthreads();
  int* prp = pairs + (size_t)p * NE + (size_t)blk * ECHUNK;
#pragma unroll
  for (int k = 0; k < EPT; ++k) {
    if (dv[k] >= 0) {
      int sl = (unsigned)dv[k] >> 8;
      int pos = scanb[sl] + atomicAdd(&hist[sl], 1);
      prp[pos] = ((dv[k] & 255) << 17) | sv[k];    // src < 2^17
    }
  }
}

// ---------------- MFMA feature GEMM (all paths) + fused el/er (unchanged) ----------------
__global__ __launch_bounds__(256) void gemm_mfma_kernel(
    const unsigned short* __restrict__ hb, const unsigned short* __restrict__ WT_all,
    const float* __restrict__ al_all, const float* __restrict__ ar_all,
    unsigned short* __restrict__ featb_all, float* __restrict__ el_all,
    float* __restrict__ er_all) {
  __shared__ unsigned short Bs[128 * 128];   // 32 KB: whole WT[p]
  const int p = blockIdx.y;
  const unsigned short* WTp = WT_all + (size_t)p * 16384;
#pragma unroll
  for (int it = 0; it < 8; ++it)
    ((float4*)Bs)[it * 256 + threadIdx.x] = ((const float4*)WTp)[it * 256 + threadIdx.x];
  __syncthreads();

  const int wid = threadIdx.x >> 6, lane = threadIdx.x & 63;
  const int c = lane & 15, q = lane >> 4;
  const int tile = blockIdx.x * 4 + wid;       // 16-row tile; NN/16 = 6250 exact
  const int tc = tile < 6250 ? tile : 6249;    // clamp for safe loads; stores guarded

  f32x4 acc[8];
#pragma unroll
  for (int t = 0; t < 8; ++t) acc[t] = (f32x4){0.f, 0.f, 0.f, 0.f};

  const unsigned short* arow = hb + (size_t)(tc * 16 + c) * 128 + q * 8;
#pragma unroll
  for (int kc = 0; kc < 4; ++kc) {
    short8 a = *(const short8*)(arow + kc * 32);
#pragma unroll
    for (int t = 0; t < 8; ++t) {
      short8 b = *(const short8*)(Bs + (size_t)(t * 16 + c) * 128 + kc * 32 + q * 8);
      acc[t] = __builtin_amdgcn_mfma_f32_16x16x32_bf16(a, b, acc[t], 0, 0, 0);
    }
  }
  if (tile >= 6250) return;

  unsigned short* featb = featb_all + (size_t)p * NN * 128;
#pragma unroll
  for (int t = 0; t < 8; ++t)
#pragma unroll
    for (int i = 0; i < 4; ++i)
      featb[(size_t)(tc * 16 + q * 4 + i) * 128 + t * 16 + c] = f2bf(acc[t][i]);

  const float* al = al_all + p * 128;
  const float* ar = ar_all + p * 128;
  float alv[8], arv[8];
#pragma unroll
  for (int t = 0; t < 8; ++t) { alv[t] = al[t * 16 + c]; arv[t] = ar[t * 16 + c]; }
  float elp[4][4], erp[4][4];   // [i][hh]
#pragma unroll
  for (int i = 0; i < 4; ++i)
#pragma unroll
    for (int hh = 0; hh < 4; ++hh) {
      elp[i][hh] = acc[2 * hh][i] * alv[2 * hh] + acc[2 * hh + 1][i] * alv[2 * hh + 1];
      erp[i][hh] = acc[2 * hh][i] * arv[2 * hh] + acc[2 * hh + 1][i] * arv[2 * hh + 1];
    }
#pragma unroll
  for (int m = 1; m <= 8; m <<= 1)
#pragma unroll
    for (int i = 0; i < 4; ++i)
#pragma unroll
      for (int hh = 0; hh < 4; ++hh) {
        elp[i][hh] += __shfl_xor(elp[i][hh], m);
        erp[i][hh] += __shfl_xor(erp[i][hh], m);
      }
  if (c == 0) {
    float* el = el_all + (size_t)p * NN * 4;
    float* er = er_all + (size_t)p * NN * 4;
#pragma unroll
    for (int i = 0; i < 4; ++i) {
      int row = tc * 16 + q * 4 + i;
      *(float4*)(el + (size_t)row * 4) = make_float4(elp[i][0], elp[i][1], elp[i][2], elp[i][3]);
      *(float4*)(er + (size_t)row * 4) = make_float4(erp[i][0], erp[i][1], erp[i][2], erp[i][3]);
    }
  }
}

// ---------------- fillB2a: per-bucket sort into dense global CSR (unchanged) ------------
__global__ __launch_bounds__(512) void fillB2a_kernel(
    const int* __restrict__ cntA, const int* __restrict__ baseA,
    const int* __restrict__ pairs, int* __restrict__ srtpk,
    int2* __restrict__ rowidx, int* __restrict__ btot) {
  __shared__ int scnt[NBLK];
  __shared__ int sbase[NBLK];
  __shared__ int scum[NBLK];
  __shared__ int totE;
  __shared__ int hist[SLW];
  __shared__ int start[SLW];
  __shared__ int wcur[SLW];
  __shared__ int earr[EMAX];
  const int tid = threadIdx.x;
  const int p = blockIdx.y, sl = blockIdx.x;
  const size_t base = ((size_t)p * GB + sl) * EMAX;

  for (int b = tid; b < NBLK; b += 512) {
    scnt[b] = cntA[((size_t)p * NBLK + b) * SBK + sl];
    sbase[b] = baseA[((size_t)p * NBLK + b) * SBK + sl];
  }
  if (tid < SLW) hist[tid] = 0;
  __syncthreads();
  if (tid < NBLK) scum[tid] = scnt[tid];
  __syncthreads();
  for (int off = 1; off < NBLK; off <<= 1) {
    int a = (tid < NBLK && tid >= off) ? scum[tid - off] : 0;
    __syncthreads();
    if (tid < NBLK) scum[tid] += a;
    __syncthreads();
  }
  if (tid == NBLK - 1) { int t = scum[NBLK - 1]; totE = t > EMAX ? EMAX : t; }
  int excl = (tid < NBLK) ? scum[tid] - scnt[tid] : 0;
  __syncthreads();
  if (tid < NBLK) scum[tid] = excl;
  __syncthreads();
  const int total = totE;
  // stage edges + node histogram
  const int* prp = pairs + (size_t)p * NE;
  for (int e = tid; e < total; e += 512) {
    int lo = 0, hi = NBLK - 1;
    while (lo < hi) { int mid = (lo + hi + 1) >> 1; if (scum[mid] <= e) lo = mid; else hi = mid - 1; }
    int pk = prp[(size_t)lo * ECHUNK + sbase[lo] + (e - scum[lo])];
    earr[e] = pk;
    atomicAdd(&hist[pk >> 17], 1);
  }
  __syncthreads();
  // scan hist -> start (exclusive); wcur = start
  if (tid < SLW) start[tid] = hist[tid];
  __syncthreads();
  for (int off = 1; off < SLW; off <<= 1) {
    int a = (tid < SLW && tid >= off) ? start[tid - off] : 0;
    __syncthreads();
    if (tid < SLW) start[tid] += a;
    __syncthreads();
  }
  if (tid < SLW) { int st = start[tid] - hist[tid]; start[tid] = st; wcur[tid] = st; }
  __syncthreads();
  // sort into global srtpk (dense region per bucket, fully populated -> clean WB)
  for (int e = tid; e < total; e += 512) {
    int pk = earr[e];
    int pos = atomicAdd(&wcur[pk >> 17], 1);
    srtpk[base + pos] = pk;
  }
  // per-node CSR entry (start/hist stable since their last barrier)
  if (tid < SLW) {
    int n = sl * SLW + tid;
    if (n < NN) rowidx[(size_t)p * NN + n] = make_int2((int)(base + start[tid]), hist[tid]);
  }
  if (tid == 0) btot[p * GB + sl] = total;
}

// ---------------- fillB2b: edge-parallel x precompute (unchanged) ----------------
__global__ __launch_bounds__(256) void fillB2b_kernel(
    const int* __restrict__ srtpk, const int* __restrict__ btot,
    const float* __restrict__ el_all, const float* __restrict__ er_all,
    float4* __restrict__ xs) {
  const int p = blockIdx.y, sl = blockIdx.x;
  const int total = btot[p * GB + sl];
  const size_t base = ((size_t)p * GB + sl) * EMAX;
  const float* el = el_all + (size_t)p * NN * 4;
  const float* er = er_all + (size_t)p * NN * 4;
  for (int i = threadIdx.x; i < total; i += 256) {
    int pk = srtpk[base + i];
    int src = pk & 0x1FFFF, dl = pk >> 17;
    int n = sl * SLW + dl;
    float4 ev = *(const float4*)(el + (size_t)src * 4);
    float4 rv = *(const float4*)(er + (size_t)n * 4);
    float4 x;
    float e0 = ev.x + rv.x; e0 = fmaxf(e0, 0.2f * e0); x.x = __expf(e0);
    float e1 = ev.y + rv.y; e1 = fmaxf(e1, 0.2f * e1); x.y = __expf(e1);
    float e2 = ev.z + rv.z; e2 = fmaxf(e2, 0.2f * e2); x.z = __expf(e2);
    float e3 = ev.w + rv.w; e3 = fmaxf(e3, 0.2f * e3); x.w = __expf(e3);
    xs[base + i] = x;
  }
}

// ---------------- gather4: quarter-wave per node, no shfl, no reduction ----------------
// R5 post-mortem: gather3 was VALU-issue-bound (77% busy, 2.5 TB/s fetch) with VALU spent
// on a vestigial pass-1 + shfl distribution (1.69M LDS conflicts) + 18-op cross-lane
// reduction, all per avg-deg-8 node on a 64-lane wave. gather4: each 16-lane quarter owns
// one node and its full 128-dim accumulator (8 dims/lane): (pk,x) read directly from the
// dense CSR (uniform per quarter -> broadcast line, L1-hot), feat 16x16B coalesced,
// dsum replicated per-lane -> ZERO cross-lane ops; 4 nodes/wave amortize prologue 4x;
// inner loop unrolled 4 edges deep for memory-level parallelism.
__global__ __launch_bounds__(256) void gather4_kernel(
    const unsigned short* __restrict__ featb_all, const int* __restrict__ srtpk,
    const float* __restrict__ xs, const int2* __restrict__ rowidx,
    const float* __restrict__ bias_all, unsigned short* __restrict__ zb) {
  const int p = blockIdx.y;
  const unsigned short* featb = featb_all + (size_t)p * NN * 128;
  const int q = threadIdx.x >> 4;            // quarter index in block (0..15)
  const int c16 = threadIdx.x & 15;
  const int hh = c16 >> 2;
  const int n = blockIdx.x * 16 + q;         // grid.x = NN/16 = 6250 exact
  int2 rd = rowidx[(size_t)p * NN + n];
  const int rbase = rd.x, deg = rd.y;

  float acc[8] = {0.f, 0.f, 0.f, 0.f, 0.f, 0.f, 0.f, 0.f};
  float dsum = 0.f;

  for (int j = 0; j < deg; j += 4) {
#pragma unroll
    for (int u = 0; u < 4; ++u) {
      int jj = j + u;
      bool v = jj < deg;
      int idx = rbase + jj;
      int pk = v ? srtpk[idx] : 0;                       // masked: avoids tail OOB
      float x = v ? xs[(size_t)idx * 4 + hh] : 0.f;
      int s = pk & 0x1FFFF;
      short8 f = *(const short8*)(featb + (size_t)s * 128 + c16 * 8);
      dsum += x;
#pragma unroll
      for (int k = 0; k < 8; ++k) acc[k] += x * bf2f((unsigned short)f[k]);
    }
  }

  float rdn = dsum > 0.f ? 1.f / dsum : 0.f;
  const float* bias = bias_all + p * 128 + c16 * 8;
  float4 b0 = *(const float4*)(bias);
  float4 b1 = *(const float4*)(bias + 4);
  short8 o;
  o[0] = f2bf(acc[0] * rdn + b0.x); o[1] = f2bf(acc[1] * rdn + b0.y);
  o[2] = f2bf(acc[2] * rdn + b0.z); o[3] = f2bf(acc[3] * rdn + b0.w);
  o[4] = f2bf(acc[4] * rdn + b1.x); o[5] = f2bf(acc[5] * rdn + b1.y);
  o[6] = f2bf(acc[6] * rdn + b1.z); o[7] = f2bf(acc[7] * rdn + b1.w);
  *(short8*)(zb + (size_t)n * (NP * 128) + p * 128 + c16 * 8) = o;
}

// ---------------- MFMA semantic scores, reduced in-kernel to s[3] (unchanged) ----------
__global__ __launch_bounds__(256) void sem_mfma_kernel(
    const unsigned short* __restrict__ zb, const unsigned short* __restrict__ W1T,
    const float* __restrict__ b1, const float* __restrict__ w2,
    float* __restrict__ s) {
  __shared__ float red3[3];
  if (threadIdx.x < 3) red3[threadIdx.x] = 0.f;
  __syncthreads();
  const int wid = threadIdx.x >> 6, lane = threadIdx.x & 63;
  const int tile = blockIdx.x * 4 + wid;       // (NN*NP)/16 = 18750 exact
  const bool active = tile < 18750;
  const int tc = active ? tile : 18749;
  const int c = lane & 15, q = lane >> 4;
  f32x4 acc[4];
#pragma unroll
  for (int t = 0; t < 4; ++t) acc[t] = (f32x4){0.f, 0.f, 0.f, 0.f};

  const unsigned short* arow = zb + (size_t)(tc * 16 + c) * 128 + q * 8;
  const unsigned short* brow = W1T + (size_t)c * 128 + q * 8;
#pragma unroll
  for (int kc = 0; kc < 4; ++kc) {
    short8 a = *(const short8*)(arow + kc * 32);
#pragma unroll
    for (int t = 0; t < 4; ++t) {
      short8 b = *(const short8*)(brow + (size_t)t * 16 * 128 + kc * 32);
      acc[t] = __builtin_amdgcn_mfma_f32_16x16x32_bf16(a, b, acc[t], 0, 0, 0);
    }
  }
  float part[4] = {0.f, 0.f, 0.f, 0.f};
#pragma unroll
  for (int t = 0; t < 4; ++t) {
    float bb = b1[t * 16 + c], ww = w2[t * 16 + c];
#pragma unroll
    for (int i = 0; i < 4; ++i) part[i] += tanh_fast(acc[t][i] + bb) * ww;
  }
#pragma unroll
  for (int m = 1; m <= 8; m <<= 1)
#pragma unroll
    for (int i = 0; i < 4; ++i) part[i] += __shfl_xor(part[i], m);
  if (active && c == 0) {
#pragma unroll
    for (int i = 0; i < 4; ++i)
      atomicAdd(&red3[(tc * 16 + q * 4 + i) % 3], part[i]);
  }
  __syncthreads();
  if (threadIdx.x < 3) atomicAdd(&s[threadIdx.x], red3[threadIdx.x]);
}

// ---------------- final combine (unchanged) ----------------
__global__ __launch_bounds__(256) void final_kernel(
    const unsigned short* __restrict__ zb, const float* __restrict__ s,
    float* __restrict__ out) {
  int i = blockIdx.x * blockDim.x + threadIdx.x;   // NN*16 threads, 8 cols each
  if (i >= NN * 16) return;
  float w0 = s[0] * (1.f / NN), w1 = s[1] * (1.f / NN), w2c = s[2] * (1.f / NN);
  float m = fmaxf(w0, fmaxf(w1, w2c));
  float e0 = __expf(w0 - m), e1 = __expf(w1 - m), e2 = __expf(w2c - m);
  float inv = 1.f / (e0 + e1 + e2);
  float b0 = e0 * inv, b1 = e1 * inv, b2 = e2 * inv;
  int n = i >> 4, g = i & 15;
  const unsigned short* zr = zb + (size_t)n * (NP * 128) + g * 8;
  ushort4 u0a = *(const ushort4*)(zr);
  ushort4 u0b = *(const ushort4*)(zr + 4);
  ushort4 u1a = *(const ushort4*)(zr + 128);
  ushort4 u1b = *(const ushort4*)(zr + 132);
  ushort4 u2a = *(const ushort4*)(zr + 256);
  ushort4 u2b = *(const ushort4*)(zr + 260);
  float4 oa, ob;
  oa.x = b0 * bf2f(u0a.x) + b1 * bf2f(u1a.x) + b2 * bf2f(u2a.x);
  oa.y = b0 * bf2f(u0a.y) + b1 * bf2f(u1a.y) + b2 * bf2f(u2a.y);
  oa.z = b0 * bf2f(u0a.z) + b1 * bf2f(u1a.z) + b2 * bf2f(u2a.z);
  oa.w = b0 * bf2f(u0a.w) + b1 * bf2f(u1a.w) + b2 * bf2f(u2a.w);
  ob.x = b0 * bf2f(u0b.x) + b1 * bf2f(u1b.x) + b2 * bf2f(u2b.x);
  ob.y = b0 * bf2f(u0b.y) + b1 * bf2f(u1b.y) + b2 * bf2f(u2b.y);
  ob.z = b0 * bf2f(u0b.z) + b1 * bf2f(u1b.z) + b2 * bf2f(u2b.z);
  ob.w = b0 * bf2f(u0b.w) + b1 * bf2f(u1b.w) + b2 * bf2f(u2b.w);
  float* op = out + (size_t)n * 128 + g * 8;
  *(float4*)op = oa;
  *(float4*)(op + 4) = ob;
}

extern "C" void kernel_launch(void* const* d_in, const int* in_sizes, int n_in,
                              void* d_out, int out_size, void* d_ws, size_t ws_size,
                              hipStream_t stream) {
  const float* h    = (const float*)d_in[0];
  const int*   esrc = (const int*)d_in[1];
  const int*   edst = (const int*)d_in[2];
  const float* W    = (const float*)d_in[3];
  const float* al   = (const float*)d_in[4];
  const float* ar   = (const float*)d_in[5];
  const float* bias = (const float*)d_in[6];
  const float* w1   = (const float*)d_in[7];
  const float* b1   = (const float*)d_in[8];
  const float* w2   = (const float*)d_in[9];
  float* out = (float*)d_out;

  // workspace layout: 221.3 MB (<= R5-proven). Region X (xs, 44.4 MB) OVERLAYS
  // cntA+baseA+pairs (dead after fillB2a) and hb (dead after gemm); fillB2b (xs writer)
  // runs after both — stream-ordered, safe.
  unsigned short* zb    = (unsigned short*)d_ws;       // 38,400,000 bf16 = 76.8 MB
  unsigned short* featb = zb + (size_t)38400000;       // 38,400,000 bf16
  unsigned short* WT    = featb + (size_t)38400000;    // 49,152 bf16
  unsigned short* W1T   = WT + 49152;                  // 8,192 bf16
  float* el   = (float*)(W1T + 8192);                  // 1,200,000 f
  float* er   = el + (size_t)1200000;                  // 1,200,000 f
  float* s    = er + (size_t)1200000;                  // 16 f
  int2* rowidx = (int2*)(s + 16);                      // NP*NN int2 = 2.4 MB
  int* btot  = (int*)(rowidx + (size_t)NP * NN);       // 1280 ints
  int* srtpk = btot + 1280;                            // NP*GB*EMAX = 2,777,664 ints
  // ---- region X ----
  int* cntA  = srtpk + (size_t)NP * GB * EMAX;         // 301,056 ints
  int* baseA = cntA + (size_t)NP * NBLK * SBK;         // 301,056 ints
  int* pairs = baseA + (size_t)NP * NBLK * SBK;        // 2,400,000 ints
  unsigned short* hb = (unsigned short*)(pairs + (size_t)NP * NE);  // 25.6 MB
  float* xs = (float*)cntA;                            // float4 view, 44.44 MB overlay

  prep_fill_kernel<<<12500 + NP * NBLK, 256, 0, stream>>>(
      h, W, w1, esrc, edst, hb, WT, W1T, s, cntA, baseA, pairs);

  dim3 bGrid(GB, NP);                                  // 391 x 3
  fillB2a_kernel<<<bGrid, 512, 0, stream>>>(cntA, baseA, pairs, srtpk, rowidx, btot);

  dim3 gemmGrid(NN / 64 + 1, NP);                      // 1563 x 3 (tiles clamped in-kernel)
  gemm_mfma_kernel<<<gemmGrid, 256, 0, stream>>>(hb, WT, al, ar, featb, el, er);

  fillB2b_kernel<<<bGrid, 256, 0, stream>>>(srtpk, btot, el, er, (float4*)xs);

  dim3 gatherGrid(NN / 16, NP);                        // 6250 x 3, 4 nodes/wave
  gather4_kernel<<<gatherGrid, 256, 0, stream>>>(featb, srtpk, xs, rowidx, bias, zb);

  sem_mfma_kernel<<<(18750 + 3) / 4, 256, 0, stream>>>(zb, W1T, b1, w2, s);
  final_kernel<<<(NN * 16 + 255) / 256, 256, 0, stream>>>(zb, s, out);
}

// Round 7
// 436.313 us; speedup vs baseline: 1.0880x; 1.0229x over previous
//
#include <hip/hip_runtime.h>
#include <hip/hip_bf16.h>
#include <math.h>

// Problem constants (from reference)
#define NN 100000      // nodes
#define NP 3           // metapaths
#define NE 800000      // edges per path
#define NH 4           // heads
#define ND 32          // dim per head
#define HD 128         // H*D
#define NHID 64        // semantic hidden

// fill/gather geometry
#define SLW 256        // nodes per bucket (pow2: sl = d>>8, dl = d&255)
#define SBK 512        // bucket slots in fillA hist (>= GB; rest stay empty)
#define GB 391         // used buckets = ceil(NN/SLW)
#define NBLK 196       // fillA blocks per path = ceil(NE/4096)
#define ECHUNK 4096    // edges per fillA block
#define EPT 16         // edges per thread in fillA (256 thr)
#define EMAX 2368      // per-bucket edge cap: mean 2048, sigma 45 -> +7.1 sigma
#define PREPB 224      // prep blocks: (NP*128*128 + NHID*128)/256 = 57344/256

typedef __attribute__((ext_vector_type(8))) short short8;
typedef __attribute__((ext_vector_type(4))) float f32x4;

__device__ __forceinline__ unsigned short f2bf(float f) {
  union { float f; unsigned int u; } v; v.f = f;
  unsigned int r = v.u + 0x7FFFu + ((v.u >> 16) & 1u);   // round-to-nearest-even
  return (unsigned short)(r >> 16);
}
__device__ __forceinline__ float bf2f(unsigned short u) {
  return __uint_as_float(((unsigned int)u) << 16);
}
__device__ __forceinline__ float tanh_fast(float x) {
  return 1.f - 2.f / (1.f + __expf(2.f * x));   // saturates correctly
}

// ---------------- prep (WT/W1T cast only) + fillA fused ----------------
// R6 change: h->bf16 cast removed (gemm2 now reads h f32 directly and casts in-reg,
// killing the hb intermediate: 51R+26W+26R -> 51R). Blocks [0,PREPB): WT/W1T transpose
// casts + zero s. Blocks [PREPB, PREPB+3*196): fillA counting compaction (validated).
__global__ __launch_bounds__(256) void prep_fill_kernel(
    const float* __restrict__ W, const float* __restrict__ W1,
    const int* __restrict__ src_all, const int* __restrict__ dst_all,
    unsigned short* __restrict__ WT, unsigned short* __restrict__ W1T,
    float* __restrict__ s,
    int* __restrict__ cntA, int* __restrict__ baseA, int* __restrict__ pairs) {
  __shared__ int hist[SBK];
  __shared__ int scanb[SBK];
  const int tid = threadIdx.x;
  const int bx = blockIdx.x;
  if (bx < PREPB) {
    int i = bx * 256 + tid;
    if (i < NP * 128 * 128) {                // WT[p][n][k] = W[p][k][n]
      int p = i >> 14, r = i & 16383, n = r >> 7, k = r & 127;
      WT[i] = f2bf(W[(size_t)p * 16384 + k * 128 + n]);
    } else {                                 // W1T[n][k] = W1[k][n]; i2 in [0,8192)
      int i2 = i - NP * 128 * 128;
      int n = i2 >> 7, k = i2 & 127;
      W1T[i2] = f2bf(W1[(size_t)k * NHID + n]);
    }
    if (bx == 0 && tid < 4) s[tid] = 0.f;
    return;
  }
  // ---- fillA: per-block-exclusive counting compaction (dense packed writes) ----
  const int b2 = bx - PREPB;
  const int p = b2 / NBLK, blk = b2 % NBLK;
  const int* dstp = dst_all + (size_t)p * NE;
  const int* srcp = src_all + (size_t)p * NE;
  hist[tid] = 0; hist[tid + 256] = 0;
  __syncthreads();
  int dv[EPT], sv[EPT];
#pragma unroll
  for (int k = 0; k < EPT; ++k) {
    int e = blk * ECHUNK + k * 256 + tid;
    dv[k] = -1; sv[k] = 0;
    if (e < NE) {
      dv[k] = __builtin_nontemporal_load(dstp + e);
      sv[k] = __builtin_nontemporal_load(srcp + e);
    }
    if (dv[k] >= 0) atomicAdd(&hist[(unsigned)dv[k] >> 8], 1);
  }
  __syncthreads();
  // inclusive scan of hist (512 entries, 2 per thread, Hillis-Steele)
  scanb[tid] = hist[tid]; scanb[tid + 256] = hist[tid + 256];
  __syncthreads();
  for (int off = 1; off < SBK; off <<= 1) {
    int a0 = (tid >= off) ? scanb[tid - off] : 0;
    int a1 = scanb[tid + 256 - off];          // tid+256 >= off always (off<=256)
    __syncthreads();
    scanb[tid] += a0; scanb[tid + 256] += a1;
    __syncthreads();
  }
  int c0 = hist[tid], c1 = hist[tid + 256];
  int b0 = scanb[tid] - c0, b1 = scanb[tid + 256] - c1;
  int* cA = cntA + ((size_t)p * NBLK + blk) * SBK;
  int* bA = baseA + ((size_t)p * NBLK + blk) * SBK;
  cA[tid] = c0; cA[tid + 256] = c1;
  bA[tid] = b0; bA[tid + 256] = b1;
  __syncthreads();
  scanb[tid] = b0; scanb[tid + 256] = b1;
  hist[tid] = 0; hist[tid + 256] = 0;
  __syncthreads();
  int* prp = pairs + (size_t)p * NE + (size_t)blk * ECHUNK;
#pragma unroll
  for (int k = 0; k < EPT; ++k) {
    if (dv[k] >= 0) {
      int sl = (unsigned)dv[k] >> 8;
      int pos = scanb[sl] + atomicAdd(&hist[sl], 1);
      prp[pos] = ((dv[k] & 255) << 17) | sv[k];    // src < 2^17
    }
  }
}

// ---------------- gemm2: all 3 paths per block, A read ONCE from f32 h ----------------
// R6 change: grid 1563 1-D; A-frags loaded once from h (f32, cast in-reg), then loop p
// staging WT[p] into the same 32KB LDS. hb read 3x -> h read 1x: saves ~100MB traffic.
__global__ __launch_bounds__(256) void gemm2_kernel(
    const float* __restrict__ h, const unsigned short* __restrict__ WT_all,
    const float* __restrict__ al_all, const float* __restrict__ ar_all,
    unsigned short* __restrict__ featb_all, float* __restrict__ el_all,
    float* __restrict__ er_all) {
  __shared__ unsigned short Bs[128 * 128];   // 32 KB, reused per path
  const int wid = threadIdx.x >> 6, lane = threadIdx.x & 63;
  const int c = lane & 15, q = lane >> 4;
  const int tile = blockIdx.x * 4 + wid;       // 16-row tile; NN/16 = 6250 exact
  const int tc = tile < 6250 ? tile : 6249;    // clamp for safe loads; stores guarded

  // load + cast A fragments once (16 f32x4 loads -> 4 short8)
  short8 afr[4];
  const float* hrow = h + (size_t)(tc * 16 + c) * 128 + q * 8;
#pragma unroll
  for (int kc = 0; kc < 4; ++kc) {
    float4 a0 = *(const float4*)(hrow + kc * 32);
    float4 a1 = *(const float4*)(hrow + kc * 32 + 4);
    short8 a;
    a[0] = (short)f2bf(a0.x); a[1] = (short)f2bf(a0.y);
    a[2] = (short)f2bf(a0.z); a[3] = (short)f2bf(a0.w);
    a[4] = (short)f2bf(a1.x); a[5] = (short)f2bf(a1.y);
    a[6] = (short)f2bf(a1.z); a[7] = (short)f2bf(a1.w);
    afr[kc] = a;
  }

  for (int p = 0; p < NP; ++p) {
    const unsigned short* WTp = WT_all + (size_t)p * 16384;
    __syncthreads();                         // previous pass done reading Bs
#pragma unroll
    for (int it = 0; it < 8; ++it)
      ((float4*)Bs)[it * 256 + threadIdx.x] = ((const float4*)WTp)[it * 256 + threadIdx.x];
    __syncthreads();

    f32x4 acc[8];
#pragma unroll
    for (int t = 0; t < 8; ++t) acc[t] = (f32x4){0.f, 0.f, 0.f, 0.f};
#pragma unroll
    for (int kc = 0; kc < 4; ++kc) {
      short8 a = afr[kc];
#pragma unroll
      for (int t = 0; t < 8; ++t) {
        short8 b = *(const short8*)(Bs + (size_t)(t * 16 + c) * 128 + kc * 32 + q * 8);
        acc[t] = __builtin_amdgcn_mfma_f32_16x16x32_bf16(a, b, acc[t], 0, 0, 0);
      }
    }
    if (tile >= 6250) continue;

    unsigned short* featb = featb_all + (size_t)p * NN * 128;
#pragma unroll
    for (int t = 0; t < 8; ++t)
#pragma unroll
      for (int i = 0; i < 4; ++i)
        featb[(size_t)(tc * 16 + q * 4 + i) * 128 + t * 16 + c] = f2bf(acc[t][i]);

    const float* al = al_all + p * 128;
    const float* ar = ar_all + p * 128;
    float alv[8], arv[8];
#pragma unroll
    for (int t = 0; t < 8; ++t) { alv[t] = al[t * 16 + c]; arv[t] = ar[t * 16 + c]; }
    float elp[4][4], erp[4][4];   // [i][hh]
#pragma unroll
    for (int i = 0; i < 4; ++i)
#pragma unroll
      for (int hh = 0; hh < 4; ++hh) {
        elp[i][hh] = acc[2 * hh][i] * alv[2 * hh] + acc[2 * hh + 1][i] * alv[2 * hh + 1];
        erp[i][hh] = acc[2 * hh][i] * arv[2 * hh] + acc[2 * hh + 1][i] * arv[2 * hh + 1];
      }
#pragma unroll
    for (int m = 1; m <= 8; m <<= 1)
#pragma unroll
      for (int i = 0; i < 4; ++i)
#pragma unroll
        for (int hh = 0; hh < 4; ++hh) {
          elp[i][hh] += __shfl_xor(elp[i][hh], m);
          erp[i][hh] += __shfl_xor(erp[i][hh], m);
        }
    if (c == 0) {
      float* el = el_all + (size_t)p * NN * 4;
      float* er = er_all + (size_t)p * NN * 4;
#pragma unroll
      for (int i = 0; i < 4; ++i) {
        int row = tc * 16 + q * 4 + i;
        *(float4*)(el + (size_t)row * 4) = make_float4(elp[i][0], elp[i][1], elp[i][2], elp[i][3]);
        *(float4*)(er + (size_t)row * 4) = make_float4(erp[i][0], erp[i][1], erp[i][2], erp[i][3]);
      }
    }
  }
}

// ---------------- fillB2a: per-bucket sort into dense global CSR (unchanged) ------------
__global__ __launch_bounds__(512) void fillB2a_kernel(
    const int* __restrict__ cntA, const int* __restrict__ baseA,
    const int* __restrict__ pairs, int* __restrict__ srtpk,
    int2* __restrict__ rowidx, int* __restrict__ btot) {
  __shared__ int scnt[NBLK];
  __shared__ int sbase[NBLK];
  __shared__ int scum[NBLK];
  __shared__ int totE;
  __shared__ int hist[SLW];
  __shared__ int start[SLW];
  __shared__ int wcur[SLW];
  __shared__ int earr[EMAX];
  const int tid = threadIdx.x;
  const int p = blockIdx.y, sl = blockIdx.x;
  const size_t base = ((size_t)p * GB + sl) * EMAX;

  for (int b = tid; b < NBLK; b += 512) {
    scnt[b] = cntA[((size_t)p * NBLK + b) * SBK + sl];
    sbase[b] = baseA[((size_t)p * NBLK + b) * SBK + sl];
  }
  if (tid < SLW) hist[tid] = 0;
  __syncthreads();
  if (tid < NBLK) scum[tid] = scnt[tid];
  __syncthreads();
  for (int off = 1; off < NBLK; off <<= 1) {
    int a = (tid < NBLK && tid >= off) ? scum[tid - off] : 0;
    __syncthreads();
    if (tid < NBLK) scum[tid] += a;
    __syncthreads();
  }
  if (tid == NBLK - 1) { int t = scum[NBLK - 1]; totE = t > EMAX ? EMAX : t; }
  int excl = (tid < NBLK) ? scum[tid] - scnt[tid] : 0;
  __syncthreads();
  if (tid < NBLK) scum[tid] = excl;
  __syncthreads();
  const int total = totE;
  // stage edges + node histogram
  const int* prp = pairs + (size_t)p * NE;
  for (int e = tid; e < total; e += 512) {
    int lo = 0, hi = NBLK - 1;
    while (lo < hi) { int mid = (lo + hi + 1) >> 1; if (scum[mid] <= e) lo = mid; else hi = mid - 1; }
    int pk = prp[(size_t)lo * ECHUNK + sbase[lo] + (e - scum[lo])];
    earr[e] = pk;
    atomicAdd(&hist[pk >> 17], 1);
  }
  __syncthreads();
  // scan hist -> start (exclusive); wcur = start
  if (tid < SLW) start[tid] = hist[tid];
  __syncthreads();
  for (int off = 1; off < SLW; off <<= 1) {
    int a = (tid < SLW && tid >= off) ? start[tid - off] : 0;
    __syncthreads();
    if (tid < SLW) start[tid] += a;
    __syncthreads();
  }
  if (tid < SLW) { int st = start[tid] - hist[tid]; start[tid] = st; wcur[tid] = st; }
  __syncthreads();
  // sort into global srtpk (dense region per bucket, fully populated -> clean WB)
  for (int e = tid; e < total; e += 512) {
    int pk = earr[e];
    int pos = atomicAdd(&wcur[pk >> 17], 1);
    srtpk[base + pos] = pk;
  }
  // per-node CSR entry (start/hist stable since their last barrier)
  if (tid < SLW) {
    int n = sl * SLW + tid;
    if (n < NN) rowidx[(size_t)p * NN + n] = make_int2((int)(base + start[tid]), hist[tid]);
  }
  if (tid == 0) btot[p * GB + sl] = total;
}

// ---------------- gather5: quarter-wave per node, x computed inline ----------------
// R6 change: fillB2b + xs eliminated. x = exp(leaky(el[src]+er[n])) computed inline —
// gather4 had VALU headroom (41% busy); exp adds ~1us chip-wide; scattered el read
// (16B/edge, 4.8MB region -> L2-resident) is independent of the feat load so its
// latency hides under the existing MLP. Saves a launch + 88MB of xs traffic.
__global__ __launch_bounds__(256) void gather5_kernel(
    const unsigned short* __restrict__ featb_all, const int* __restrict__ srtpk,
    const float* __restrict__ el_all, const float* __restrict__ er_all,
    const int2* __restrict__ rowidx, const float* __restrict__ bias_all,
    unsigned short* __restrict__ zb) {
  const int p = blockIdx.y;
  const unsigned short* featb = featb_all + (size_t)p * NN * 128;
  const float* el = el_all + (size_t)p * NN * 4;
  const int q = threadIdx.x >> 4;            // quarter index in block (0..15)
  const int c16 = threadIdx.x & 15;
  const int hh = c16 >> 2;
  const int n = blockIdx.x * 16 + q;         // grid.x = NN/16 = 6250 exact
  int2 rd = rowidx[(size_t)p * NN + n];
  const int rbase = rd.x, deg = rd.y;
  const float ern = er_all[((size_t)p * NN + n) * 4 + hh];

  float acc[8] = {0.f, 0.f, 0.f, 0.f, 0.f, 0.f, 0.f, 0.f};
  float dsum = 0.f;

  for (int j = 0; j < deg; j += 4) {
#pragma unroll
    for (int u = 0; u < 4; ++u) {
      int jj = j + u;
      bool v = jj < deg;
      int idx = rbase + jj;
      int pk = v ? srtpk[idx] : 0;                       // masked: avoids tail OOB
      int s = pk & 0x1FFFF;
      float x = 0.f;
      if (v) {
        float e = el[(size_t)s * 4 + hh] + ern;
        e = fmaxf(e, 0.2f * e);
        x = __expf(e);
      }
      short8 f = *(const short8*)(featb + (size_t)s * 128 + c16 * 8);
      dsum += x;
#pragma unroll
      for (int k = 0; k < 8; ++k) acc[k] += x * bf2f((unsigned short)f[k]);
    }
  }

  float rdn = dsum > 0.f ? 1.f / dsum : 0.f;
  const float* bias = bias_all + p * 128 + c16 * 8;
  float4 b0 = *(const float4*)(bias);
  float4 b1 = *(const float4*)(bias + 4);
  short8 o;
  o[0] = f2bf(acc[0] * rdn + b0.x); o[1] = f2bf(acc[1] * rdn + b0.y);
  o[2] = f2bf(acc[2] * rdn + b0.z); o[3] = f2bf(acc[3] * rdn + b0.w);
  o[4] = f2bf(acc[4] * rdn + b1.x); o[5] = f2bf(acc[5] * rdn + b1.y);
  o[6] = f2bf(acc[6] * rdn + b1.z); o[7] = f2bf(acc[7] * rdn + b1.w);
  *(short8*)(zb + (size_t)n * (NP * 128) + p * 128 + c16 * 8) = o;
}

// ---------------- MFMA semantic scores, reduced in-kernel to s[3] (unchanged) ----------
__global__ __launch_bounds__(256) void sem_mfma_kernel(
    const unsigned short* __restrict__ zb, const unsigned short* __restrict__ W1T,
    const float* __restrict__ b1, const float* __restrict__ w2,
    float* __restrict__ s) {
  __shared__ float red3[3];
  if (threadIdx.x < 3) red3[threadIdx.x] = 0.f;
  __syncthreads();
  const int wid = threadIdx.x >> 6, lane = threadIdx.x & 63;
  const int tile = blockIdx.x * 4 + wid;       // (NN*NP)/16 = 18750 exact
  const bool active = tile < 18750;
  const int tc = active ? tile : 18749;
  const int c = lane & 15, q = lane >> 4;
  f32x4 acc[4];
#pragma unroll
  for (int t = 0; t < 4; ++t) acc[t] = (f32x4){0.f, 0.f, 0.f, 0.f};

  const unsigned short* arow = zb + (size_t)(tc * 16 + c) * 128 + q * 8;
  const unsigned short* brow = W1T + (size_t)c * 128 + q * 8;
#pragma unroll
  for (int kc = 0; kc < 4; ++kc) {
    short8 a = *(const short8*)(arow + kc * 32);
#pragma unroll
    for (int t = 0; t < 4; ++t) {
      short8 b = *(const short8*)(brow + (size_t)t * 16 * 128 + kc * 32);
      acc[t] = __builtin_amdgcn_mfma_f32_16x16x32_bf16(a, b, acc[t], 0, 0, 0);
    }
  }
  float part[4] = {0.f, 0.f, 0.f, 0.f};
#pragma unroll
  for (int t = 0; t < 4; ++t) {
    float bb = b1[t * 16 + c], ww = w2[t * 16 + c];
#pragma unroll
    for (int i = 0; i < 4; ++i) part[i] += tanh_fast(acc[t][i] + bb) * ww;
  }
#pragma unroll
  for (int m = 1; m <= 8; m <<= 1)
#pragma unroll
    for (int i = 0; i < 4; ++i) part[i] += __shfl_xor(part[i], m);
  if (active && c == 0) {
#pragma unroll
    for (int i = 0; i < 4; ++i)
      atomicAdd(&red3[(tc * 16 + q * 4 + i) % 3], part[i]);
  }
  __syncthreads();
  if (threadIdx.x < 3) atomicAdd(&s[threadIdx.x], red3[threadIdx.x]);
}

// ---------------- final combine (unchanged) ----------------
__global__ __launch_bounds__(256) void final_kernel(
    const unsigned short* __restrict__ zb, const float* __restrict__ s,
    float* __restrict__ out) {
  int i = blockIdx.x * blockDim.x + threadIdx.x;   // NN*16 threads, 8 cols each
  if (i >= NN * 16) return;
  float w0 = s[0] * (1.f / NN), w1 = s[1] * (1.f / NN), w2c = s[2] * (1.f / NN);
  float m = fmaxf(w0, fmaxf(w1, w2c));
  float e0 = __expf(w0 - m), e1 = __expf(w1 - m), e2 = __expf(w2c - m);
  float inv = 1.f / (e0 + e1 + e2);
  float b0 = e0 * inv, b1 = e1 * inv, b2 = e2 * inv;
  int n = i >> 4, g = i & 15;
  const unsigned short* zr = zb + (size_t)n * (NP * 128) + g * 8;
  ushort4 u0a = *(const ushort4*)(zr);
  ushort4 u0b = *(const ushort4*)(zr + 4);
  ushort4 u1a = *(const ushort4*)(zr + 128);
  ushort4 u1b = *(const ushort4*)(zr + 132);
  ushort4 u2a = *(const ushort4*)(zr + 256);
  ushort4 u2b = *(const ushort4*)(zr + 260);
  float4 oa, ob;
  oa.x = b0 * bf2f(u0a.x) + b1 * bf2f(u1a.x) + b2 * bf2f(u2a.x);
  oa.y = b0 * bf2f(u0a.y) + b1 * bf2f(u1a.y) + b2 * bf2f(u2a.y);
  oa.z = b0 * bf2f(u0a.z) + b1 * bf2f(u1a.z) + b2 * bf2f(u2a.z);
  oa.w = b0 * bf2f(u0a.w) + b1 * bf2f(u1a.w) + b2 * bf2f(u2a.w);
  ob.x = b0 * bf2f(u0b.x) + b1 * bf2f(u1b.x) + b2 * bf2f(u2b.x);
  ob.y = b0 * bf2f(u0b.y) + b1 * bf2f(u1b.y) + b2 * bf2f(u2b.y);
  ob.z = b0 * bf2f(u0b.z) + b1 * bf2f(u1b.z) + b2 * bf2f(u2b.z);
  ob.w = b0 * bf2f(u0b.w) + b1 * bf2f(u1b.w) + b2 * bf2f(u2b.w);
  float* op = out + (size_t)n * 128 + g * 8;
  *(float4*)op = oa;
  *(float4*)(op + 4) = ob;
}

extern "C" void kernel_launch(void* const* d_in, const int* in_sizes, int n_in,
                              void* d_out, int out_size, void* d_ws, size_t ws_size,
                              hipStream_t stream) {
  const float* h    = (const float*)d_in[0];
  const int*   esrc = (const int*)d_in[1];
  const int*   edst = (const int*)d_in[2];
  const float* W    = (const float*)d_in[3];
  const float* al   = (const float*)d_in[4];
  const float* ar   = (const float*)d_in[5];
  const float* bias = (const float*)d_in[6];
  const float* w1   = (const float*)d_in[7];
  const float* b1   = (const float*)d_in[8];
  const float* w2   = (const float*)d_in[9];
  float* out = (float*)d_out;

  // workspace layout: ~184 MB, NO overlays (hb and xs eliminated this round)
  unsigned short* zb    = (unsigned short*)d_ws;       // 38,400,000 bf16 = 76.8 MB
  unsigned short* featb = zb + (size_t)38400000;       // 38,400,000 bf16
  unsigned short* WT    = featb + (size_t)38400000;    // 49,152 bf16
  unsigned short* W1T   = WT + 49152;                  // 8,192 bf16
  float* el   = (float*)(W1T + 8192);                  // 1,200,000 f
  float* er   = el + (size_t)1200000;                  // 1,200,000 f
  float* s    = er + (size_t)1200000;                  // 16 f
  int2* rowidx = (int2*)(s + 16);                      // NP*NN int2 = 2.4 MB
  int* btot  = (int*)(rowidx + (size_t)NP * NN);       // 1280 ints
  int* srtpk = btot + 1280;                            // NP*GB*EMAX = 2,777,664 ints
  int* cntA  = srtpk + (size_t)NP * GB * EMAX;         // 301,056 ints
  int* baseA = cntA + (size_t)NP * NBLK * SBK;         // 301,056 ints
  int* pairs = baseA + (size_t)NP * NBLK * SBK;        // 2,400,000 ints

  prep_fill_kernel<<<PREPB + NP * NBLK, 256, 0, stream>>>(
      W, w1, esrc, edst, WT, W1T, s, cntA, baseA, pairs);

  dim3 bGrid(GB, NP);                                  // 391 x 3
  fillB2a_kernel<<<bGrid, 512, 0, stream>>>(cntA, baseA, pairs, srtpk, rowidx, btot);

  gemm2_kernel<<<1563, 256, 0, stream>>>(h, WT, al, ar, featb, el, er);

  dim3 gatherGrid(NN / 16, NP);                        // 6250 x 3, 4 nodes/wave
  gather5_kernel<<<gatherGrid, 256, 0, stream>>>(featb, srtpk, el, er, rowidx, bias, zb);

  sem_mfma_kernel<<<(18750 + 3) / 4, 256, 0, stream>>>(zb, W1T, b1, w2, s);
  final_kernel<<<(NN * 16 + 255) / 256, 256, 0, stream>>>(zb, s, out);
}